// Round 2
// baseline (5319.308 us; speedup 1.0000x reference)
//
#include <hip/hip_runtime.h>
#include <cstddef>

#define HID 4096
#define NH 1024
#define LDA 1088   // augmented LU matrix leading dim: 1024 cols + rhs col (1024) + 63 zero-pad cols

__device__ __forceinline__ float wred(float a) {
#pragma unroll
  for (int off = 32; off > 0; off >>= 1) a += __shfl_down(a, off);
  return a;
}

// ---------------- forward / backward vector pipeline ----------------

__global__ __launch_bounds__(256) void k_zero(float* __restrict__ a, float* __restrict__ b,
                                              float* __restrict__ c) {
  int i = blockIdx.x * 256 + threadIdx.x;  // 4096
  a[i] = 0.f; b[i] = 0.f; c[i] = 0.f;
}

// z1 partial: split-K over rows of W1 (atomics into zb)
__global__ __launch_bounds__(256) void k_z1p(const float* __restrict__ x, const float* __restrict__ W1,
                                             float* __restrict__ zb) {
  int k = blockIdx.x * 256 + threadIdx.x;
  int i0 = blockIdx.y * 256;
  float acc = 0.f;
  for (int i = i0; i < i0 + 256; ++i) acc = fmaf(x[i], W1[(size_t)i * HID + k], acc);
  atomicAdd(&zb[k], acc);
}

__global__ __launch_bounds__(256) void k_act1(const float* __restrict__ zb, const float* __restrict__ b1,
                                              float* __restrict__ h1, float* __restrict__ s1,
                                              float* __restrict__ s1p) {
  int k = blockIdx.x * 256 + threadIdx.x;
  float z = zb[k] + b1[k];
  float sg = 1.f / (1.f + expf(-z));
  h1[k] = (z > 20.f) ? z : log1pf(expf(z));
  s1[k] = sg;
  s1p[k] = sg * (1.f - sg);
}

__global__ __launch_bounds__(256) void k_z2p(const float* __restrict__ h1, const float* __restrict__ W2,
                                             float* __restrict__ zb) {
  int j = blockIdx.x * 256 + threadIdx.x;
  int i0 = blockIdx.y * 256;
  float acc = 0.f;
  for (int i = i0; i < i0 + 256; ++i) acc = fmaf(h1[i], W2[(size_t)i * HID + j], acc);
  atomicAdd(&zb[j], acc);
}

__global__ __launch_bounds__(256) void k_act2(const float* __restrict__ zb, const float* __restrict__ b2,
                                              const float* __restrict__ w3, float* __restrict__ g2,
                                              float* __restrict__ d2) {
  int j = blockIdx.x * 256 + threadIdx.x;
  float z = zb[j] + b2[j];
  float sg = 1.f / (1.f + expf(-z));
  float w = w3[j];
  g2[j] = sg * w;
  d2[j] = sg * (1.f - sg) * w;
}

// u = W2 @ g2 ; g1 = s1*u ; d1 = s1p*u   (wave per row of W2)
__global__ __launch_bounds__(256) void k_u(const float* __restrict__ W2, const float* __restrict__ g2,
                                           const float* __restrict__ s1, const float* __restrict__ s1p,
                                           float* __restrict__ g1, float* __restrict__ d1) {
  int w = threadIdx.x >> 6, lane = threadIdx.x & 63;
  int row = blockIdx.x * 4 + w;
  const float* p = W2 + (size_t)row * HID;
  float acc = 0.f;
  for (int j = lane; j < HID; j += 64) acc = fmaf(p[j], g2[j], acc);
  acc = wred(acc);
  if (lane == 0) {
    g1[row] = s1[row] * acc;
    d1[row] = s1p[row] * acc;
  }
}

// dq0 = (W1 @ g1)[:1024]   (wave per row)
__global__ __launch_bounds__(256) void k_dq0(const float* __restrict__ W1, const float* __restrict__ g1,
                                             float* __restrict__ dq0) {
  int w = threadIdx.x >> 6, lane = threadIdx.x & 63;
  int row = blockIdx.x * 4 + w;
  const float* p = W1 + (size_t)row * HID;
  float acc = 0.f;
  for (int k = lane; k < HID; k += 64) acc = fmaf(p[k], g1[k], acc);
  acc = wred(acc);
  if (lane == 0) dq0[row] = acc;
}

// v_l = sum_r QT[r,l] * x[1024+r]   (split over r, atomics)
__global__ __launch_bounds__(256) void k_vp(const float* __restrict__ QT, const float* __restrict__ x,
                                            float* __restrict__ v) {
  int l = blockIdx.x * 256 + threadIdx.x;
  int r0 = blockIdx.y * 128;
  float acc = 0.f;
  for (int r = r0; r < r0 + 128; ++r) acc = fmaf(QT[(size_t)r * HID + l], x[NH + r], acc);
  atomicAdd(&v[l], acc);
}

// rhs_i = dq0_i - sum_l W1a[i,l] v_l
__global__ __launch_bounds__(256) void k_rhs(const float* __restrict__ W1, const float* __restrict__ v,
                                             const float* __restrict__ dq0, float* __restrict__ rhs) {
  int w = threadIdx.x >> 6, lane = threadIdx.x & 63;
  int row = blockIdx.x * 4 + w;
  const float* p = W1 + (size_t)row * HID;
  float acc = 0.f;
  for (int l = lane; l < HID; l += 64) acc = fmaf(p[l], v[l], acc);
  acc = wred(acc);
  if (lane == 0) rhs[row] = dq0[row] - acc;
}

// ---------------- fp32 tiled GEMM (128x128 tile, BK=16, 8x8/thread) ----------------
// C[m,n] = sum_k A[m,k]*Bmat(k,n),  Bmat(k,n) = TRANSB ? B[n*ldb+k] : B[k*ldb+n]
// MODE 0: C = acc
// MODE 1: A scaled by kscale[k] at load; C = acc*csc1[col]
// MODE 2: C = acc*csc1[col] + csc2[col]*wadd[row*HID+col]
template <bool TRANSB, int MODE>
__global__ __launch_bounds__(256) void gemm_k(const float* __restrict__ A, int lda,
                                              const float* __restrict__ B, int ldb,
                                              float* __restrict__ C, int ldc, int K,
                                              const float* __restrict__ kscale,
                                              const float* __restrict__ csc1,
                                              const float* __restrict__ csc2,
                                              const float* __restrict__ wadd) {
  __shared__ float As[16][132];
  __shared__ float Bs[16][132];
  int tid = threadIdx.x;
  int bm = blockIdx.y * 128, bn = blockIdx.x * 128;
  int ra = tid >> 1, ka = (tid & 1) * 8;
  int tm = (tid >> 4) * 8, tn = (tid & 15) * 8;
  float acc[8][8];
#pragma unroll
  for (int i = 0; i < 8; ++i)
#pragma unroll
    for (int j = 0; j < 8; ++j) acc[i][j] = 0.f;

  for (int k0 = 0; k0 < K; k0 += 16) {
    float4 a0 = *(const float4*)(A + (size_t)(bm + ra) * lda + k0 + ka);
    float4 a1 = *(const float4*)(A + (size_t)(bm + ra) * lda + k0 + ka + 4);
    if (MODE == 1) {
      a0.x *= kscale[k0 + ka + 0]; a0.y *= kscale[k0 + ka + 1];
      a0.z *= kscale[k0 + ka + 2]; a0.w *= kscale[k0 + ka + 3];
      a1.x *= kscale[k0 + ka + 4]; a1.y *= kscale[k0 + ka + 5];
      a1.z *= kscale[k0 + ka + 6]; a1.w *= kscale[k0 + ka + 7];
    }
    As[ka + 0][ra] = a0.x; As[ka + 1][ra] = a0.y; As[ka + 2][ra] = a0.z; As[ka + 3][ra] = a0.w;
    As[ka + 4][ra] = a1.x; As[ka + 5][ra] = a1.y; As[ka + 6][ra] = a1.z; As[ka + 7][ra] = a1.w;
    if (TRANSB) {
      float4 b0 = *(const float4*)(B + (size_t)(bn + ra) * ldb + k0 + ka);
      float4 b1 = *(const float4*)(B + (size_t)(bn + ra) * ldb + k0 + ka + 4);
      Bs[ka + 0][ra] = b0.x; Bs[ka + 1][ra] = b0.y; Bs[ka + 2][ra] = b0.z; Bs[ka + 3][ra] = b0.w;
      Bs[ka + 4][ra] = b1.x; Bs[ka + 5][ra] = b1.y; Bs[ka + 6][ra] = b1.z; Bs[ka + 7][ra] = b1.w;
    } else {
      int kb = tid >> 4, nb = (tid & 15) * 8;
      float4 b0 = *(const float4*)(B + (size_t)(k0 + kb) * ldb + bn + nb);
      float4 b1 = *(const float4*)(B + (size_t)(k0 + kb) * ldb + bn + nb + 4);
      *(float4*)&Bs[kb][nb] = b0;
      *(float4*)&Bs[kb][nb + 4] = b1;
    }
    __syncthreads();
#pragma unroll
    for (int kk = 0; kk < 16; ++kk) {
      float4 x0 = *(const float4*)&As[kk][tm];
      float4 x1 = *(const float4*)&As[kk][tm + 4];
      float4 y0 = *(const float4*)&Bs[kk][tn];
      float4 y1 = *(const float4*)&Bs[kk][tn + 4];
      float av[8] = {x0.x, x0.y, x0.z, x0.w, x1.x, x1.y, x1.z, x1.w};
      float bv[8] = {y0.x, y0.y, y0.z, y0.w, y1.x, y1.y, y1.z, y1.w};
#pragma unroll
      for (int i = 0; i < 8; ++i)
#pragma unroll
        for (int j = 0; j < 8; ++j) acc[i][j] = fmaf(av[i], bv[j], acc[i][j]);
    }
    __syncthreads();
  }
#pragma unroll
  for (int i = 0; i < 8; ++i) {
    int row = bm + tm + i;
    float out[8];
#pragma unroll
    for (int j = 0; j < 8; ++j) {
      int col = bn + tn + j;
      float vv = acc[i][j];
      if (MODE == 1) vv *= csc1[col];
      if (MODE == 2) vv = vv * csc1[col] + csc2[col] * wadd[(size_t)row * HID + col];
      out[j] = vv;
    }
    *(float4*)(C + (size_t)row * ldc + bn + tn) = *(float4*)&out[0];
    *(float4*)(C + (size_t)row * ldc + bn + tn + 4) = *(float4*)&out[4];
  }
}

// ---------------- augmented-matrix setup ----------------
__global__ __launch_bounds__(256) void k_setup(const float* __restrict__ dq1, const float* __restrict__ rhs,
                                               float* __restrict__ Ag) {
  int idx = blockIdx.x * 256 + threadIdx.x;  // 1024*1088
  int r = idx / LDA, c = idx % LDA;
  float v = (c < 1024) ? dq1[(size_t)r * 1024 + c] : (c == 1024 ? rhs[r] : 0.f);
  Ag[idx] = v;
}

// ---------------- blocked LU (NB=64, no pivoting), rhs as augmented col ----------------

__global__ __launch_bounds__(64) void lu_diag(float* __restrict__ Ag, int o) {
  __shared__ float T[64][65];
  int t = threadIdx.x;
  for (int r = 0; r < 64; ++r) T[r][t] = Ag[(size_t)(o + r) * LDA + o + t];
  __syncthreads();
  for (int kk = 0; kk < 63; ++kk) {
    if (t > kk) {
      float l = T[t][kk] / T[kk][kk];
      T[t][kk] = l;
      for (int c = kk + 1; c < 64; ++c) T[t][c] = fmaf(-l, T[kk][c], T[t][c]);
    }
    __syncthreads();
  }
  for (int r = 0; r < 64; ++r) Ag[(size_t)(o + r) * LDA + o + t] = T[r][t];
}

// U12 = L11^-1 A12 (per 64-col tile; includes rhs + pad cols)
__global__ __launch_bounds__(128) void lu_u12(float* __restrict__ Ag, int o) {
  __shared__ float L[64][65];
  __shared__ float X[64][65];
  int t = threadIdx.x, cl = t & 63, ch = t >> 6;
  int c0 = o + 64 + blockIdx.x * 64;
  for (int r = ch; r < 64; r += 2) {
    L[r][cl] = Ag[(size_t)(o + r) * LDA + o + cl];
    X[r][cl] = Ag[(size_t)(o + r) * LDA + c0 + cl];
  }
  __syncthreads();
  for (int kk = 0; kk < 63; ++kk) {
    float xk = X[kk][cl];
    for (int i = kk + 1 + ch; i < 64; i += 2) X[i][cl] = fmaf(-L[i][kk], xk, X[i][cl]);
    __syncthreads();
  }
  for (int r = ch; r < 64; r += 2) Ag[(size_t)(o + r) * LDA + c0 + cl] = X[r][cl];
}

// L21 = A21 U11^-1 (per 64-row tile; rows fully thread-private, no barriers in loop)
__global__ __launch_bounds__(64) void lu_l21(float* __restrict__ Ag, int o) {
  __shared__ float U[64][65];
  __shared__ float Y[64][65];
  __shared__ float rp[64];
  int t = threadIdx.x;
  int r0 = o + 64 + blockIdx.x * 64;
  for (int r = 0; r < 64; ++r) {
    U[r][t] = Ag[(size_t)(o + r) * LDA + o + t];
    Y[r][t] = Ag[(size_t)(r0 + r) * LDA + o + t];
  }
  __syncthreads();
  rp[t] = 1.f / U[t][t];
  __syncthreads();
  for (int kk = 0; kk < 64; ++kk) {
    float val = Y[t][kk] * rp[kk];
    Y[t][kk] = val;
    for (int m = kk + 1; m < 64; ++m) Y[t][m] = fmaf(-val, U[kk][m], Y[t][m]);
  }
  __syncthreads();
  for (int r = 0; r < 64; ++r) Ag[(size_t)(r0 + r) * LDA + o + t] = Y[r][t];
}

// A22 -= L21 @ U12  (64x64 tiles, K=64)
__global__ __launch_bounds__(256) void lu_schur(float* __restrict__ Ag, int o) {
  __shared__ float Ls[64][65];  // Ls[k][r]
  __shared__ float Us[64][65];  // Us[k][c]
  int t = threadIdx.x;
  int c0 = o + 64 + blockIdx.x * 64;
  int r0 = o + 64 + blockIdx.y * 64;
  for (int idx = t; idx < 4096; idx += 256) {
    int r = idx >> 6, q = idx & 63;
    Ls[q][r] = Ag[(size_t)(r0 + r) * LDA + o + q];
    Us[r][q] = Ag[(size_t)(o + r) * LDA + c0 + q];
  }
  __syncthreads();
  int tm = (t >> 4) * 4, tn = (t & 15) * 4;
  float acc[4][4];
#pragma unroll
  for (int i = 0; i < 4; ++i)
#pragma unroll
    for (int j = 0; j < 4; ++j) acc[i][j] = 0.f;
#pragma unroll 8
  for (int kk = 0; kk < 64; ++kk) {
    float a[4], b[4];
#pragma unroll
    for (int i = 0; i < 4; ++i) a[i] = Ls[kk][tm + i];
#pragma unroll
    for (int j = 0; j < 4; ++j) b[j] = Us[kk][tn + j];
#pragma unroll
    for (int i = 0; i < 4; ++i)
#pragma unroll
      for (int j = 0; j < 4; ++j) acc[i][j] = fmaf(a[i], b[j], acc[i][j]);
  }
#pragma unroll
  for (int i = 0; i < 4; ++i)
#pragma unroll
    for (int j = 0; j < 4; ++j) Ag[(size_t)(r0 + tm + i) * LDA + c0 + tn + j] -= acc[i][j];
}

// ---------------- triangular solves on contiguous vectors ----------------

__global__ __launch_bounds__(256) void k_copycol(const float* __restrict__ Ag, float* __restrict__ y) {
  int i = blockIdx.x * 256 + threadIdx.x;  // 1024
  y[i] = Ag[(size_t)i * LDA + 1024];
}

__global__ __launch_bounds__(64) void bs_diag(const float* __restrict__ Ag, float* __restrict__ y, int o) {
  __shared__ float T[64][65];
  __shared__ float rp[64];
  __shared__ float ys[64];
  int t = threadIdx.x;
  for (int r = 0; r < 64; ++r) T[r][t] = Ag[(size_t)(o + r) * LDA + o + t];
  ys[t] = y[o + t];
  __syncthreads();
  rp[t] = 1.f / T[t][t];
  __syncthreads();
  for (int kk = 63; kk >= 0; --kk) {
    float xk = ys[kk] * rp[kk];
    __syncthreads();
    if (t == kk) ys[t] = xk;
    else if (t < kk) ys[t] = fmaf(-T[t][kk], xk, ys[t]);
    __syncthreads();
  }
  y[o + t] = ys[t];
}

__global__ __launch_bounds__(256) void bs_update(const float* __restrict__ Ag, float* __restrict__ y, int o) {
  int w = threadIdx.x >> 6, lane = threadIdx.x & 63;
  int row = blockIdx.x * 4 + w;  // rows 0..o-1
  float a = Ag[(size_t)row * LDA + o + lane] * y[o + lane];
  a = wred(a);
  if (lane == 0) y[row] -= a;
}

__global__ __launch_bounds__(64) void fs_diag(const float* __restrict__ Ag, float* __restrict__ y, int o) {
  __shared__ float T[64][65];
  __shared__ float ys[64];
  int t = threadIdx.x;
  for (int r = 0; r < 64; ++r) T[r][t] = Ag[(size_t)(o + r) * LDA + o + t];
  ys[t] = y[o + t];
  __syncthreads();
  for (int kk = 0; kk < 63; ++kk) {
    __syncthreads();
    float xk = ys[kk];
    if (t > kk) ys[t] = fmaf(-T[t][kk], xk, ys[t]);
  }
  __syncthreads();
  y[o + t] = ys[t];
}

__global__ __launch_bounds__(256) void fs_update(const float* __restrict__ Ag, float* __restrict__ y, int o) {
  int w = threadIdx.x >> 6, lane = threadIdx.x & 63;
  int row = o + 64 + blockIdx.x * 4 + w;
  float a = Ag[(size_t)row * LDA + o + lane] * y[o + lane];
  a = wred(a);
  if (lane == 0) y[row] -= a;
}

// residual r = rhs - dq1 @ x0
__global__ __launch_bounds__(256) void k_resid(const float* __restrict__ dq1, const float* __restrict__ x0,
                                               const float* __restrict__ rhs, float* __restrict__ rv) {
  int w = threadIdx.x >> 6, lane = threadIdx.x & 63;
  int row = blockIdx.x * 4 + w;
  const float* p = dq1 + (size_t)row * 1024;
  float acc = 0.f;
  for (int j = lane; j < 1024; j += 64) acc = fmaf(p[j], x0[j], acc);
  acc = wred(acc);
  if (lane == 0) rv[row] = rhs[row] - acc;
}

__global__ __launch_bounds__(256) void k_final(const float* __restrict__ yb, const float* __restrict__ rv,
                                               float* __restrict__ out) {
  int i = blockIdx.x * 256 + threadIdx.x;  // 1024
  out[i] = yb[i] + rv[i];
}

// ---------------- launcher ----------------

extern "C" void kernel_launch(void* const* d_in, const int* in_sizes, int n_in, void* d_out,
                              int out_size, void* d_ws, size_t ws_size, hipStream_t stream) {
  const float* x  = (const float*)d_in[0];
  const float* W1 = (const float*)d_in[1];
  const float* b1 = (const float*)d_in[2];
  const float* W2 = (const float*)d_in[3];
  const float* b2 = (const float*)d_in[4];
  const float* W3 = (const float*)d_in[5];
  float* out = (float*)d_out;
  float* ws = (float*)d_ws;

  // workspace layout (floats); total ~42.5 MiB
  float* h1  = ws + 0;
  float* s1  = ws + 4096;
  float* s1p = ws + 8192;
  float* d1  = ws + 12288;
  float* g2  = ws + 16384;
  float* d2  = ws + 20480;
  float* g1  = ws + 24576;
  float* zb1 = ws + 28672;
  float* zb2 = ws + 32768;
  float* vv  = ws + 36864;
  float* dq0 = ws + 40960;
  float* rhs = ws + 41984;
  float* yb  = ws + 43008;
  float* rv  = ws + 44032;
  float* Bbs = ws + 65536;
  float* QT  = Bbs + (size_t)1024 * HID;
  float* Ag  = QT + (size_t)1024 * HID;
  float* dq1 = Ag + (size_t)1024 * LDA;

  const float* W1b = W1 + (size_t)NH * HID;

  // forward + backward vectors
  k_zero<<<16, 256, 0, stream>>>(zb1, zb2, vv);
  k_z1p<<<dim3(16, 8), 256, 0, stream>>>(x, W1, zb1);
  k_act1<<<16, 256, 0, stream>>>(zb1, b1, h1, s1, s1p);
  k_z2p<<<dim3(16, 16), 256, 0, stream>>>(h1, W2, zb2);
  k_act2<<<16, 256, 0, stream>>>(zb2, b2, W3, g2, d2);
  k_u<<<1024, 256, 0, stream>>>(W2, g2, s1, s1p, g1, d1);
  k_dq0<<<256, 256, 0, stream>>>(W1, g1, dq0);

  // Hessian blocks: Bbs = (W1b*s1)@W2 * D2 ; QT = D1*W1b + s1*(Bbs@W2^T) ; dq1 = W1b@QT^T
  gemm_k<false, 1><<<dim3(32, 8), 256, 0, stream>>>(W1b, HID, W2, HID, Bbs, HID, HID, s1, d2, nullptr, nullptr);
  gemm_k<true, 2><<<dim3(32, 8), 256, 0, stream>>>(Bbs, HID, W2, HID, QT, HID, HID, nullptr, s1, d1, W1b);
  gemm_k<true, 0><<<dim3(8, 8), 256, 0, stream>>>(W1b, HID, QT, HID, dq1, 1024, HID, nullptr, nullptr, nullptr, nullptr);

  // rhs = dq0 - dq2 @ x[n:]  via v = QT^T @ x[n:]
  k_vp<<<dim3(16, 8), 256, 0, stream>>>(QT, x, vv);
  k_rhs<<<256, 256, 0, stream>>>(W1, vv, dq0, rhs);
  k_setup<<<(1024 * LDA) / 256, 256, 0, stream>>>(dq1, rhs, Ag);

  // blocked LU, rhs carried in augmented column
  for (int kb = 0; kb < 16; ++kb) {
    int o = kb * 64;
    lu_diag<<<1, 64, 0, stream>>>(Ag, o);
    int ncols = 1024 - o;  // cols right of diag block (incl. rhs + pad)
    lu_u12<<<ncols / 64, 128, 0, stream>>>(Ag, o);
    int nrows = 960 - o;
    if (nrows > 0) {
      lu_l21<<<nrows / 64, 64, 0, stream>>>(Ag, o);
      lu_schur<<<dim3(ncols / 64, nrows / 64), 256, 0, stream>>>(Ag, o);
    }
  }

  // back substitution: yb = U^-1 (L^-1 rhs)
  k_copycol<<<4, 256, 0, stream>>>(Ag, yb);
  for (int kb = 15; kb >= 0; --kb) {
    int o = kb * 64;
    bs_diag<<<1, 64, 0, stream>>>(Ag, yb, o);
    if (o > 0) bs_update<<<o / 4, 256, 0, stream>>>(Ag, yb, o);
  }

  // one iterative-refinement pass (no-pivot LU insurance)
  k_resid<<<256, 256, 0, stream>>>(dq1, yb, rhs, rv);
  for (int kb = 0; kb < 16; ++kb) {
    int o = kb * 64;
    fs_diag<<<1, 64, 0, stream>>>(Ag, rv, o);
    int nrows = 960 - o;
    if (nrows > 0) fs_update<<<nrows / 4, 256, 0, stream>>>(Ag, rv, o);
  }
  for (int kb = 15; kb >= 0; --kb) {
    int o = kb * 64;
    bs_diag<<<1, 64, 0, stream>>>(Ag, rv, o);
    if (o > 0) bs_update<<<o / 4, 256, 0, stream>>>(Ag, rv, o);
  }
  k_final<<<4, 256, 0, stream>>>(yb, rv, out);
}

// Round 5
// 5214.093 us; speedup vs baseline: 1.0202x; 1.0202x over previous
//
#include <hip/hip_runtime.h>
#include <cstddef>

#define HID 4096
#define NH 1024
#define LDA 1088   // augmented LU matrix: 1024 cols + rhs col + 63 pad cols

__device__ __forceinline__ float wred(float a) {
#pragma unroll
  for (int off = 32; off > 0; off >>= 1) a += __shfl_down(a, off);
  return a;
}

// ---------------- forward / backward vector pipeline (deterministic: no atomics) ----------------

// z1 partials: block (bx,by) writes zp1[by*HID + k], k = bx*256+t, rows by*256..+255
__global__ __launch_bounds__(256) void k_z1p(const float* __restrict__ x, const float* __restrict__ W1,
                                             float* __restrict__ zp1) {
  int k = blockIdx.x * 256 + threadIdx.x;
  int i0 = blockIdx.y * 256;
  float acc = 0.f;
  for (int i = i0; i < i0 + 256; ++i) acc = fmaf(x[i], W1[(size_t)i * HID + k], acc);
  zp1[(size_t)blockIdx.y * HID + k] = acc;
}

// fixed-order reduce of 8 partials + activation
__global__ __launch_bounds__(256) void k_act1(const float* __restrict__ zp1, const float* __restrict__ b1,
                                              float* __restrict__ h1, float* __restrict__ s1,
                                              float* __restrict__ s1p) {
  int k = blockIdx.x * 256 + threadIdx.x;
  float z = b1[k];
#pragma unroll
  for (int j = 0; j < 8; ++j) z += zp1[(size_t)j * HID + k];
  float sg = 1.f / (1.f + expf(-z));
  h1[k] = (z > 20.f) ? z : log1pf(expf(z));
  s1[k] = sg;
  s1p[k] = sg * (1.f - sg);
}

// z2 partials: 16 splits of 256 rows
__global__ __launch_bounds__(256) void k_z2p(const float* __restrict__ h1, const float* __restrict__ W2,
                                             float* __restrict__ zp2) {
  int j = blockIdx.x * 256 + threadIdx.x;
  int i0 = blockIdx.y * 256;
  float acc = 0.f;
  for (int i = i0; i < i0 + 256; ++i) acc = fmaf(h1[i], W2[(size_t)i * HID + j], acc);
  zp2[(size_t)blockIdx.y * HID + j] = acc;
}

__global__ __launch_bounds__(256) void k_act2(const float* __restrict__ zp2, const float* __restrict__ b2,
                                              const float* __restrict__ w3, float* __restrict__ g2,
                                              float* __restrict__ d2) {
  int j = blockIdx.x * 256 + threadIdx.x;
  float z = b2[j];
#pragma unroll
  for (int q = 0; q < 16; ++q) z += zp2[(size_t)q * HID + j];
  float sg = 1.f / (1.f + expf(-z));
  float w = w3[j];
  g2[j] = sg * w;
  d2[j] = sg * (1.f - sg) * w;
}

__global__ __launch_bounds__(256) void k_u(const float* __restrict__ W2, const float* __restrict__ g2,
                                           const float* __restrict__ s1, const float* __restrict__ s1p,
                                           float* __restrict__ g1, float* __restrict__ d1) {
  int w = threadIdx.x >> 6, lane = threadIdx.x & 63;
  int row = blockIdx.x * 4 + w;
  const float* p = W2 + (size_t)row * HID;
  float acc = 0.f;
  for (int j = lane; j < HID; j += 64) acc = fmaf(p[j], g2[j], acc);
  acc = wred(acc);
  if (lane == 0) {
    g1[row] = s1[row] * acc;
    d1[row] = s1p[row] * acc;
  }
}

__global__ __launch_bounds__(256) void k_dq0(const float* __restrict__ W1, const float* __restrict__ g1,
                                             float* __restrict__ dq0) {
  int w = threadIdx.x >> 6, lane = threadIdx.x & 63;
  int row = blockIdx.x * 4 + w;
  const float* p = W1 + (size_t)row * HID;
  float acc = 0.f;
  for (int k = lane; k < HID; k += 64) acc = fmaf(p[k], g1[k], acc);
  acc = wred(acc);
  if (lane == 0) dq0[row] = acc;
}

// vp[by*HID + l] = sum over 128 rows of QT[r,l]*xb_r  (deterministic partials)
__global__ __launch_bounds__(256) void k_vp(const float* __restrict__ QT, const float* __restrict__ x,
                                            float* __restrict__ vp) {
  int l = blockIdx.x * 256 + threadIdx.x;
  int r0 = blockIdx.y * 128;
  float acc = 0.f;
  for (int r = r0; r < r0 + 128; ++r) acc = fmaf(QT[(size_t)r * HID + l], x[NH + r], acc);
  vp[(size_t)blockIdx.y * HID + l] = acc;
}

// vv[l] = fixed-order sum of 8 partials
__global__ __launch_bounds__(256) void k_vred(const float* __restrict__ vp, float* __restrict__ vv) {
  int l = blockIdx.x * 256 + threadIdx.x;
  float a = 0.f;
#pragma unroll
  for (int j = 0; j < 8; ++j) a += vp[(size_t)j * HID + l];
  vv[l] = a;
}

// rhs_i = dq0_i - sum_l W1a[i,l] vv_l
__global__ __launch_bounds__(256) void k_rhs(const float* __restrict__ W1, const float* __restrict__ v,
                                             const float* __restrict__ dq0, float* __restrict__ rhs) {
  int w = threadIdx.x >> 6, lane = threadIdx.x & 63;
  int row = blockIdx.x * 4 + w;
  const float* p = W1 + (size_t)row * HID;
  float acc = 0.f;
  for (int l = lane; l < HID; l += 64) acc = fmaf(p[l], v[l], acc);
  acc = wred(acc);
  if (lane == 0) rhs[row] = dq0[row] - acc;
}

// ---------------- fp32 tiled GEMM (128x128 tile, BK=16, 8x8/thread) ----------------
// C[m,n] = sum_k A[m,k]*Bmat(k,n),  Bmat(k,n) = TRANSB ? B[n*ldb+k] : B[k*ldb+n]
// MODE 0: C = acc
// MODE 1: A scaled by kscale[k] at load; C = acc*csc1[col]
// MODE 2: C = acc*csc1[col] + csc2[col]*wadd[row*HID+col]
template <bool TRANSB, int MODE>
__global__ __launch_bounds__(256) void gemm_k(const float* __restrict__ A, int lda,
                                              const float* __restrict__ B, int ldb,
                                              float* __restrict__ C, int ldc, int K,
                                              const float* __restrict__ kscale,
                                              const float* __restrict__ csc1,
                                              const float* __restrict__ csc2,
                                              const float* __restrict__ wadd) {
  __shared__ float As[16][132];
  __shared__ float Bs[16][132];
  int tid = threadIdx.x;
  int bm = blockIdx.y * 128, bn = blockIdx.x * 128;
  int ra = tid >> 1, ka = (tid & 1) * 8;
  int tm = (tid >> 4) * 8, tn = (tid & 15) * 8;
  float acc[8][8];
#pragma unroll
  for (int i = 0; i < 8; ++i)
#pragma unroll
    for (int j = 0; j < 8; ++j) acc[i][j] = 0.f;

  for (int k0 = 0; k0 < K; k0 += 16) {
    float4 a0 = *(const float4*)(A + (size_t)(bm + ra) * lda + k0 + ka);
    float4 a1 = *(const float4*)(A + (size_t)(bm + ra) * lda + k0 + ka + 4);
    if (MODE == 1) {
      a0.x *= kscale[k0 + ka + 0]; a0.y *= kscale[k0 + ka + 1];
      a0.z *= kscale[k0 + ka + 2]; a0.w *= kscale[k0 + ka + 3];
      a1.x *= kscale[k0 + ka + 4]; a1.y *= kscale[k0 + ka + 5];
      a1.z *= kscale[k0 + ka + 6]; a1.w *= kscale[k0 + ka + 7];
    }
    As[ka + 0][ra] = a0.x; As[ka + 1][ra] = a0.y; As[ka + 2][ra] = a0.z; As[ka + 3][ra] = a0.w;
    As[ka + 4][ra] = a1.x; As[ka + 5][ra] = a1.y; As[ka + 6][ra] = a1.z; As[ka + 7][ra] = a1.w;
    if (TRANSB) {
      float4 b0 = *(const float4*)(B + (size_t)(bn + ra) * ldb + k0 + ka);
      float4 b1 = *(const float4*)(B + (size_t)(bn + ra) * ldb + k0 + ka + 4);
      Bs[ka + 0][ra] = b0.x; Bs[ka + 1][ra] = b0.y; Bs[ka + 2][ra] = b0.z; Bs[ka + 3][ra] = b0.w;
      Bs[ka + 4][ra] = b1.x; Bs[ka + 5][ra] = b1.y; Bs[ka + 6][ra] = b1.z; Bs[ka + 7][ra] = b1.w;
    } else {
      int kb = tid >> 4, nb = (tid & 15) * 8;
      float4 b0 = *(const float4*)(B + (size_t)(k0 + kb) * ldb + bn + nb);
      float4 b1 = *(const float4*)(B + (size_t)(k0 + kb) * ldb + bn + nb + 4);
      *(float4*)&Bs[kb][nb] = b0;
      *(float4*)&Bs[kb][nb + 4] = b1;
    }
    __syncthreads();
#pragma unroll
    for (int kk = 0; kk < 16; ++kk) {
      float4 x0 = *(const float4*)&As[kk][tm];
      float4 x1 = *(const float4*)&As[kk][tm + 4];
      float4 y0 = *(const float4*)&Bs[kk][tn];
      float4 y1 = *(const float4*)&Bs[kk][tn + 4];
      float av[8] = {x0.x, x0.y, x0.z, x0.w, x1.x, x1.y, x1.z, x1.w};
      float bv[8] = {y0.x, y0.y, y0.z, y0.w, y1.x, y1.y, y1.z, y1.w};
#pragma unroll
      for (int i = 0; i < 8; ++i)
#pragma unroll
        for (int j = 0; j < 8; ++j) acc[i][j] = fmaf(av[i], bv[j], acc[i][j]);
    }
    __syncthreads();
  }
#pragma unroll
  for (int i = 0; i < 8; ++i) {
    int row = bm + tm + i;
    float out[8];
#pragma unroll
    for (int j = 0; j < 8; ++j) {
      int col = bn + tn + j;
      float vv = acc[i][j];
      if (MODE == 1) vv *= csc1[col];
      if (MODE == 2) vv = vv * csc1[col] + csc2[col] * wadd[(size_t)row * HID + col];
      out[j] = vv;
    }
    *(float4*)(C + (size_t)row * ldc + bn + tn) = *(float4*)&out[0];
    *(float4*)(C + (size_t)row * ldc + bn + tn + 4) = *(float4*)&out[4];
  }
}

// ---------------- augmented-matrix setup ----------------
__global__ __launch_bounds__(256) void k_setup(const float* __restrict__ dq1, const float* __restrict__ rhs,
                                               float* __restrict__ Ag) {
  int idx = blockIdx.x * 256 + threadIdx.x;  // 1024*1088
  int r = idx / LDA, c = idx % LDA;
  float v = (c < 1024) ? dq1[(size_t)r * 1024 + c] : (c == 1024 ? rhs[r] : 0.f);
  Ag[idx] = v;
}

// ---------------- blocked LU (NB=64, no pivoting), rhs as augmented col ----------------

// diag tile factor: 256 threads, rank-1 update form
__global__ __launch_bounds__(256) void lu_diag(float* __restrict__ Ag, int o) {
  __shared__ float T[64][65];
  int t = threadIdx.x;
  for (int idx = t; idx < 4096; idx += 256) {
    int r = idx >> 6, c = idx & 63;
    T[r][c] = Ag[(size_t)(o + r) * LDA + o + c];
  }
  __syncthreads();
  int r = t & 63, cg = t >> 6;
  for (int kk = 0; kk < 63; ++kk) {
    if (cg == 0 && r > kk) T[r][kk] /= T[kk][kk];
    __syncthreads();
    float l = (r > kk) ? T[r][kk] : 0.f;
    int c0 = cg * 16;
#pragma unroll
    for (int j = 0; j < 16; ++j) {
      int c = c0 + j;
      if (r > kk && c > kk) T[r][c] = fmaf(-l, T[kk][c], T[r][c]);
    }
    __syncthreads();
  }
  for (int idx = t; idx < 4096; idx += 256) {
    int rr = idx >> 6, c = idx & 63;
    Ag[(size_t)(o + rr) * LDA + o + c] = T[rr][c];
  }
}

// fused panel: blocks [0,NU) do U12 tiles (L^-1 * A12), blocks [NU,..) do L21 tiles (A21 * U^-1)
__global__ __launch_bounds__(256) void lu_panel(float* __restrict__ Ag, int o, int NU) {
  __shared__ float Ds[64][65];
  __shared__ float Xs[64][65];
  __shared__ float rp[64];
  int t = threadIdx.x;
  bool isU = (int)blockIdx.x < NU;
  size_t tb;
  if (isU) tb = (size_t)o * LDA + (o + 64 + (int)blockIdx.x * 64);
  else     tb = (size_t)(o + 64 + ((int)blockIdx.x - NU) * 64) * LDA + o;
  for (int idx = t; idx < 4096; idx += 256) {
    int r = idx >> 6, c = idx & 63;
    Ds[r][c] = Ag[(size_t)(o + r) * LDA + o + c];
    Xs[r][c] = Ag[tb + (size_t)r * LDA + c];
  }
  __syncthreads();
  if (!isU && t < 64) rp[t] = 1.f / Ds[t][t];
  __syncthreads();
  if (isU) {
    int cl = t & 63, rg = t >> 6;
    for (int kk = 0; kk < 63; ++kk) {
      float xk = Xs[kk][cl];
      int i0 = rg * 16;
#pragma unroll
      for (int j = 0; j < 16; ++j) {
        int i = i0 + j;
        if (i > kk) Xs[i][cl] = fmaf(-Ds[i][kk], xk, Xs[i][cl]);
      }
      __syncthreads();
    }
  } else {
    int r = t & 63, cg = t >> 6;
    for (int kk = 0; kk < 64; ++kk) {
      if (cg == (kk >> 4)) Xs[r][kk] *= rp[kk];
      __syncthreads();
      float vk = Xs[r][kk];
      int c0 = cg * 16;
#pragma unroll
      for (int j = 0; j < 16; ++j) {
        int m = c0 + j;
        if (m > kk) Xs[r][m] = fmaf(-vk, Ds[kk][m], Xs[r][m]);
      }
      __syncthreads();
    }
  }
  __syncthreads();
  for (int idx = t; idx < 4096; idx += 256) {
    int r = idx >> 6, c = idx & 63;
    Ag[tb + (size_t)r * LDA + c] = Xs[r][c];
  }
}

// A22 -= L21 @ U12  (64x64 tiles, K=64)
__global__ __launch_bounds__(256) void lu_schur(float* __restrict__ Ag, int o) {
  __shared__ float Ls[64][65];
  __shared__ float Us[64][65];
  int t = threadIdx.x;
  int c0 = o + 64 + blockIdx.x * 64;
  int r0 = o + 64 + blockIdx.y * 64;
  for (int idx = t; idx < 4096; idx += 256) {
    int r = idx >> 6, q = idx & 63;
    Ls[q][r] = Ag[(size_t)(r0 + r) * LDA + o + q];
    Us[r][q] = Ag[(size_t)(o + r) * LDA + c0 + q];
  }
  __syncthreads();
  int tm = (t >> 4) * 4, tn = (t & 15) * 4;
  float acc[4][4];
#pragma unroll
  for (int i = 0; i < 4; ++i)
#pragma unroll
    for (int j = 0; j < 4; ++j) acc[i][j] = 0.f;
#pragma unroll 8
  for (int kk = 0; kk < 64; ++kk) {
    float a[4], b[4];
#pragma unroll
    for (int i = 0; i < 4; ++i) a[i] = Ls[kk][tm + i];
#pragma unroll
    for (int j = 0; j < 4; ++j) b[j] = Us[kk][tn + j];
#pragma unroll
    for (int i = 0; i < 4; ++i)
#pragma unroll
      for (int j = 0; j < 4; ++j) acc[i][j] = fmaf(a[i], b[j], acc[i][j]);
  }
#pragma unroll
  for (int i = 0; i < 4; ++i)
#pragma unroll
    for (int j = 0; j < 4; ++j) Ag[(size_t)(r0 + tm + i) * LDA + c0 + tn + j] -= acc[i][j];
}

// ---------------- whole-triangular-solve kernels (single block) ----------------

// back substitution U x = (augmented rhs col, already forward-substituted); writes yb
__global__ __launch_bounds__(256) void bs_all(const float* __restrict__ Ag, float* __restrict__ yb) {
  __shared__ float ys[1024];
  __shared__ float Td[64][65];
  int t = threadIdx.x;
  for (int i = t; i < 1024; i += 256) ys[i] = Ag[(size_t)i * LDA + 1024];
  __syncthreads();
  for (int kb = 15; kb >= 0; --kb) {
    int o = kb * 64;
    for (int idx = t; idx < 4096; idx += 256) {
      int r = idx >> 6, c = idx & 63;
      Td[r][c] = Ag[(size_t)(o + r) * LDA + o + c];
    }
    __syncthreads();
    if (t < 64) {
      float yv = ys[o + t];
      float rpv = 1.f / Td[t][t];
#pragma unroll 16
      for (int kk = 63; kk >= 0; --kk) {
        float xk = __shfl(yv * rpv, kk, 64);
        if (t == kk) yv = xk;
        else if (t < kk) yv = fmaf(-Td[t][kk], xk, yv);
      }
      ys[o + t] = yv;
    }
    __syncthreads();
    if (o > 0) {
      int c = t & 63, wg = t >> 6;
      float yc = ys[o + c];
      for (int rr = wg; rr < o; rr += 16) {
        float p0 = Ag[(size_t)rr * LDA + o + c] * yc;
        float p1 = Ag[(size_t)(rr + 4) * LDA + o + c] * yc;
        float p2 = Ag[(size_t)(rr + 8) * LDA + o + c] * yc;
        float p3 = Ag[(size_t)(rr + 12) * LDA + o + c] * yc;
        p0 = wred(p0); p1 = wred(p1); p2 = wred(p2); p3 = wred(p3);
        if (c == 0) { ys[rr] -= p0; ys[rr + 4] -= p1; ys[rr + 8] -= p2; ys[rr + 12] -= p3; }
      }
      __syncthreads();
    }
  }
  for (int i = t; i < 1024; i += 256) yb[i] = ys[i];
}

// residual r = rhs - dq1 @ yb
__global__ __launch_bounds__(256) void k_resid(const float* __restrict__ dq1, const float* __restrict__ x0,
                                               const float* __restrict__ rhs, float* __restrict__ rv) {
  int w = threadIdx.x >> 6, lane = threadIdx.x & 63;
  int row = blockIdx.x * 4 + w;
  const float* p = dq1 + (size_t)row * 1024;
  float acc = 0.f;
  for (int j = lane; j < 1024; j += 64) acc = fmaf(p[j], x0[j], acc);
  acc = wred(acc);
  if (lane == 0) rv[row] = rhs[row] - acc;
}

// refinement: forward (unit L) + backward (U) solve of rv, then out = yb + correction
__global__ __launch_bounds__(256) void fsbs_all(const float* __restrict__ Ag, const float* __restrict__ rv,
                                                const float* __restrict__ yb, float* __restrict__ out) {
  __shared__ float ys[1024];
  __shared__ float Td[64][65];
  int t = threadIdx.x;
  for (int i = t; i < 1024; i += 256) ys[i] = rv[i];
  __syncthreads();
  // forward substitution (unit lower)
  for (int kb = 0; kb < 16; ++kb) {
    int o = kb * 64;
    for (int idx = t; idx < 4096; idx += 256) {
      int r = idx >> 6, c = idx & 63;
      Td[r][c] = Ag[(size_t)(o + r) * LDA + o + c];
    }
    __syncthreads();
    if (t < 64) {
      float yv = ys[o + t];
#pragma unroll 16
      for (int kk = 0; kk < 63; ++kk) {
        float xk = __shfl(yv, kk, 64);
        if (t > kk) yv = fmaf(-Td[t][kk], xk, yv);
      }
      ys[o + t] = yv;
    }
    __syncthreads();
    if (o < 960) {
      int c = t & 63, wg = t >> 6;
      float yc = ys[o + c];
      for (int rr = o + 64 + wg; rr < 1024; rr += 16) {
        float p0 = Ag[(size_t)rr * LDA + o + c] * yc;
        float p1 = Ag[(size_t)(rr + 4) * LDA + o + c] * yc;
        float p2 = Ag[(size_t)(rr + 8) * LDA + o + c] * yc;
        float p3 = Ag[(size_t)(rr + 12) * LDA + o + c] * yc;
        p0 = wred(p0); p1 = wred(p1); p2 = wred(p2); p3 = wred(p3);
        if (c == 0) { ys[rr] -= p0; ys[rr + 4] -= p1; ys[rr + 8] -= p2; ys[rr + 12] -= p3; }
      }
      __syncthreads();
    }
  }
  // back substitution
  for (int kb = 15; kb >= 0; --kb) {
    int o = kb * 64;
    for (int idx = t; idx < 4096; idx += 256) {
      int r = idx >> 6, c = idx & 63;
      Td[r][c] = Ag[(size_t)(o + r) * LDA + o + c];
    }
    __syncthreads();
    if (t < 64) {
      float yv = ys[o + t];
      float rpv = 1.f / Td[t][t];
#pragma unroll 16
      for (int kk = 63; kk >= 0; --kk) {
        float xk = __shfl(yv * rpv, kk, 64);
        if (t == kk) yv = xk;
        else if (t < kk) yv = fmaf(-Td[t][kk], xk, yv);
      }
      ys[o + t] = yv;
    }
    __syncthreads();
    if (o > 0) {
      int c = t & 63, wg = t >> 6;
      float yc = ys[o + c];
      for (int rr = wg; rr < o; rr += 16) {
        float p0 = Ag[(size_t)rr * LDA + o + c] * yc;
        float p1 = Ag[(size_t)(rr + 4) * LDA + o + c] * yc;
        float p2 = Ag[(size_t)(rr + 8) * LDA + o + c] * yc;
        float p3 = Ag[(size_t)(rr + 12) * LDA + o + c] * yc;
        p0 = wred(p0); p1 = wred(p1); p2 = wred(p2); p3 = wred(p3);
        if (c == 0) { ys[rr] -= p0; ys[rr + 4] -= p1; ys[rr + 8] -= p2; ys[rr + 12] -= p3; }
      }
      __syncthreads();
    }
  }
  for (int i = t; i < 1024; i += 256) out[i] = yb[i] + ys[i];
}

// ---------------- launcher ----------------

extern "C" void kernel_launch(void* const* d_in, const int* in_sizes, int n_in, void* d_out,
                              int out_size, void* d_ws, size_t ws_size, hipStream_t stream) {
  const float* x  = (const float*)d_in[0];
  const float* W1 = (const float*)d_in[1];
  const float* b1 = (const float*)d_in[2];
  const float* W2 = (const float*)d_in[3];
  const float* b2 = (const float*)d_in[4];
  const float* W3 = (const float*)d_in[5];
  float* out = (float*)d_out;
  float* ws = (float*)d_ws;

  // workspace layout (floats); same high-water as round 2 (~40.5 MiB)
  float* h1  = ws + 0;
  float* s1  = ws + 4096;
  float* s1p = ws + 8192;
  float* d1  = ws + 12288;
  float* g2  = ws + 16384;
  float* d2  = ws + 20480;
  float* g1  = ws + 24576;
  float* vv  = ws + 28672;
  float* dq0 = ws + 32768;
  float* rhs = ws + 33792;
  float* yb  = ws + 34816;
  float* rv  = ws + 35840;
  float* Bbs = ws + 65536;
  float* QT  = Bbs + (size_t)1024 * HID;
  float* Ag  = QT + (size_t)1024 * HID;
  float* dq1 = Ag + (size_t)1024 * LDA;

  // deterministic-reduction partial buffers, aliased into Ag (dead until k_setup)
  float* zp1 = Ag;            //  8 x 4096
  float* zp2 = Ag + 32768;    // 16 x 4096
  float* vp  = Ag + 98304;    //  8 x 4096

  const float* W1b = W1 + (size_t)NH * HID;

  // forward + backward vectors (no atomics anywhere)
  k_z1p<<<dim3(16, 8), 256, 0, stream>>>(x, W1, zp1);
  k_act1<<<16, 256, 0, stream>>>(zp1, b1, h1, s1, s1p);
  k_z2p<<<dim3(16, 16), 256, 0, stream>>>(h1, W2, zp2);
  k_act2<<<16, 256, 0, stream>>>(zp2, b2, W3, g2, d2);
  k_u<<<1024, 256, 0, stream>>>(W2, g2, s1, s1p, g1, d1);
  k_dq0<<<256, 256, 0, stream>>>(W1, g1, dq0);

  // Hessian blocks: Bbs = (W1b*s1)@W2 * D2 ; QT = s1*(Bbs@W2^T) + d1*W1b ; dq1 = W1b@QT^T
  gemm_k<false, 1><<<dim3(32, 8), 256, 0, stream>>>(W1b, HID, W2, HID, Bbs, HID, HID, s1, d2, nullptr, nullptr);
  gemm_k<true, 2><<<dim3(32, 8), 256, 0, stream>>>(Bbs, HID, W2, HID, QT, HID, HID, nullptr, s1, d1, W1b);
  gemm_k<true, 0><<<dim3(8, 8), 256, 0, stream>>>(W1b, HID, QT, HID, dq1, 1024, HID, nullptr, nullptr, nullptr, nullptr);

  // rhs = dq0 - dq2 @ x[n:]  via vv = QT^T @ x[n:]
  k_vp<<<dim3(16, 8), 256, 0, stream>>>(QT, x, vp);
  k_vred<<<16, 256, 0, stream>>>(vp, vv);
  k_rhs<<<256, 256, 0, stream>>>(W1, vv, dq0, rhs);
  k_setup<<<(1024 * LDA) / 256, 256, 0, stream>>>(dq1, rhs, Ag);

  // blocked LU, rhs carried in augmented column
  for (int kb = 0; kb < 16; ++kb) {
    int o = kb * 64;
    int NU = 16 - kb;   // col tiles right of diag (incl rhs+pad tile)
    int NL = 15 - kb;   // row tiles below diag
    lu_diag<<<1, 256, 0, stream>>>(Ag, o);
    lu_panel<<<NU + NL, 256, 0, stream>>>(Ag, o, NU);
    if (NL > 0) lu_schur<<<dim3(NU, NL), 256, 0, stream>>>(Ag, o);
  }

  // solve + one iterative-refinement pass
  bs_all<<<1, 256, 0, stream>>>(Ag, yb);
  k_resid<<<256, 256, 0, stream>>>(dq1, yb, rhs, rv);
  fsbs_all<<<1, 256, 0, stream>>>(Ag, rv, yb, out);
}

// Round 6
// 4900.486 us; speedup vs baseline: 1.0855x; 1.0640x over previous
//
#include <hip/hip_runtime.h>
#include <cstddef>

#define HID 4096
#define NH 1024
#define LDA 1088   // augmented LU matrix: 1024 cols + rhs col + 63 pad cols

__device__ __forceinline__ float wred(float a) {
#pragma unroll
  for (int off = 32; off > 0; off >>= 1) a += __shfl_down(a, off);
  return a;
}

// ---------------- forward / backward vector pipeline (deterministic: no atomics) ----------------

__global__ __launch_bounds__(256) void k_z1p(const float* __restrict__ x, const float* __restrict__ W1,
                                             float* __restrict__ zp1) {
  int k = blockIdx.x * 256 + threadIdx.x;
  int i0 = blockIdx.y * 256;
  float acc = 0.f;
  for (int i = i0; i < i0 + 256; ++i) acc = fmaf(x[i], W1[(size_t)i * HID + k], acc);
  zp1[(size_t)blockIdx.y * HID + k] = acc;
}

__global__ __launch_bounds__(256) void k_act1(const float* __restrict__ zp1, const float* __restrict__ b1,
                                              float* __restrict__ h1, float* __restrict__ s1,
                                              float* __restrict__ s1p) {
  int k = blockIdx.x * 256 + threadIdx.x;
  float z = b1[k];
#pragma unroll
  for (int j = 0; j < 8; ++j) z += zp1[(size_t)j * HID + k];
  float sg = 1.f / (1.f + expf(-z));
  h1[k] = (z > 20.f) ? z : log1pf(expf(z));
  s1[k] = sg;
  s1p[k] = sg * (1.f - sg);
}

__global__ __launch_bounds__(256) void k_z2p(const float* __restrict__ h1, const float* __restrict__ W2,
                                             float* __restrict__ zp2) {
  int j = blockIdx.x * 256 + threadIdx.x;
  int i0 = blockIdx.y * 256;
  float acc = 0.f;
  for (int i = i0; i < i0 + 256; ++i) acc = fmaf(h1[i], W2[(size_t)i * HID + j], acc);
  zp2[(size_t)blockIdx.y * HID + j] = acc;
}

__global__ __launch_bounds__(256) void k_act2(const float* __restrict__ zp2, const float* __restrict__ b2,
                                              const float* __restrict__ w3, float* __restrict__ g2,
                                              float* __restrict__ d2) {
  int j = blockIdx.x * 256 + threadIdx.x;
  float z = b2[j];
#pragma unroll
  for (int q = 0; q < 16; ++q) z += zp2[(size_t)q * HID + j];
  float sg = 1.f / (1.f + expf(-z));
  float w = w3[j];
  g2[j] = sg * w;
  d2[j] = sg * (1.f - sg) * w;
}

__global__ __launch_bounds__(256) void k_u(const float* __restrict__ W2, const float* __restrict__ g2,
                                           const float* __restrict__ s1, const float* __restrict__ s1p,
                                           float* __restrict__ g1, float* __restrict__ d1) {
  int w = threadIdx.x >> 6, lane = threadIdx.x & 63;
  int row = blockIdx.x * 4 + w;
  const float* p = W2 + (size_t)row * HID;
  float acc = 0.f;
  for (int j = lane; j < HID; j += 64) acc = fmaf(p[j], g2[j], acc);
  acc = wred(acc);
  if (lane == 0) {
    g1[row] = s1[row] * acc;
    d1[row] = s1p[row] * acc;
  }
}

__global__ __launch_bounds__(256) void k_dq0(const float* __restrict__ W1, const float* __restrict__ g1,
                                             float* __restrict__ dq0) {
  int w = threadIdx.x >> 6, lane = threadIdx.x & 63;
  int row = blockIdx.x * 4 + w;
  const float* p = W1 + (size_t)row * HID;
  float acc = 0.f;
  for (int k = lane; k < HID; k += 64) acc = fmaf(p[k], g1[k], acc);
  acc = wred(acc);
  if (lane == 0) dq0[row] = acc;
}

__global__ __launch_bounds__(256) void k_vp(const float* __restrict__ QT, const float* __restrict__ x,
                                            float* __restrict__ vp) {
  int l = blockIdx.x * 256 + threadIdx.x;
  int r0 = blockIdx.y * 128;
  float acc = 0.f;
  for (int r = r0; r < r0 + 128; ++r) acc = fmaf(QT[(size_t)r * HID + l], x[NH + r], acc);
  vp[(size_t)blockIdx.y * HID + l] = acc;
}

__global__ __launch_bounds__(256) void k_vred(const float* __restrict__ vp, float* __restrict__ vv) {
  int l = blockIdx.x * 256 + threadIdx.x;
  float a = 0.f;
#pragma unroll
  for (int j = 0; j < 8; ++j) a += vp[(size_t)j * HID + l];
  vv[l] = a;
}

__global__ __launch_bounds__(256) void k_rhs(const float* __restrict__ W1, const float* __restrict__ v,
                                             const float* __restrict__ dq0, float* __restrict__ rhs) {
  int w = threadIdx.x >> 6, lane = threadIdx.x & 63;
  int row = blockIdx.x * 4 + w;
  const float* p = W1 + (size_t)row * HID;
  float acc = 0.f;
  for (int l = lane; l < HID; l += 64) acc = fmaf(p[l], v[l], acc);
  acc = wred(acc);
  if (lane == 0) rhs[row] = dq0[row] - acc;
}

// ---------------- fp32 tiled GEMM: 128x64 tile, BK=16, 4x8/thread (retile of round-5) ----------------
// C[m,n] = sum_k Ahat[m,k]*Bmat(k,n),  Bmat(k,n) = TRANSB ? B[n*ldb+k] : B[k*ldb+n]
// MODE 0: C = acc
// MODE 1: A scaled by kscale[k] at load; C = acc*csc1[col]
// MODE 2: C = acc*csc1[col] + csc2[col]*wadd[row*HID+col]
template <bool TRANSB, int MODE>
__global__ __launch_bounds__(256) void gemm_k(const float* __restrict__ A, int lda,
                                              const float* __restrict__ B, int ldb,
                                              float* __restrict__ C, int ldc, int K,
                                              const float* __restrict__ kscale,
                                              const float* __restrict__ csc1,
                                              const float* __restrict__ csc2,
                                              const float* __restrict__ wadd) {
  __shared__ float As[16][132];
  __shared__ float Bs[16][68];
  int tid = threadIdx.x;
  int bm = blockIdx.y * 128, bn = blockIdx.x * 64;
  int ra = tid >> 1, ka = (tid & 1) * 8;
  int tm = (tid >> 3) * 4, tn = (tid & 7) * 8;
  float acc[4][8];
#pragma unroll
  for (int i = 0; i < 4; ++i)
#pragma unroll
    for (int j = 0; j < 8; ++j) acc[i][j] = 0.f;

  for (int k0 = 0; k0 < K; k0 += 16) {
    float4 a0 = *(const float4*)(A + (size_t)(bm + ra) * lda + k0 + ka);
    float4 a1 = *(const float4*)(A + (size_t)(bm + ra) * lda + k0 + ka + 4);
    if (MODE == 1) {
      a0.x *= kscale[k0 + ka + 0]; a0.y *= kscale[k0 + ka + 1];
      a0.z *= kscale[k0 + ka + 2]; a0.w *= kscale[k0 + ka + 3];
      a1.x *= kscale[k0 + ka + 4]; a1.y *= kscale[k0 + ka + 5];
      a1.z *= kscale[k0 + ka + 6]; a1.w *= kscale[k0 + ka + 7];
    }
    As[ka + 0][ra] = a0.x; As[ka + 1][ra] = a0.y; As[ka + 2][ra] = a0.z; As[ka + 3][ra] = a0.w;
    As[ka + 4][ra] = a1.x; As[ka + 5][ra] = a1.y; As[ka + 6][ra] = a1.z; As[ka + 7][ra] = a1.w;
    if (TRANSB) {
      int rb = tid >> 2, kb = (tid & 3) * 4;
      float4 b0 = *(const float4*)(B + (size_t)(bn + rb) * ldb + k0 + kb);
      Bs[kb + 0][rb] = b0.x; Bs[kb + 1][rb] = b0.y; Bs[kb + 2][rb] = b0.z; Bs[kb + 3][rb] = b0.w;
    } else {
      int kb = tid >> 4, nb = (tid & 15) * 4;
      *(float4*)&Bs[kb][nb] = *(const float4*)(B + (size_t)(k0 + kb) * ldb + bn + nb);
    }
    __syncthreads();
#pragma unroll
    for (int kk = 0; kk < 16; ++kk) {
      float4 x0 = *(const float4*)&As[kk][tm];
      float4 y0 = *(const float4*)&Bs[kk][tn];
      float4 y1 = *(const float4*)&Bs[kk][tn + 4];
      float av[4] = {x0.x, x0.y, x0.z, x0.w};
      float bv[8] = {y0.x, y0.y, y0.z, y0.w, y1.x, y1.y, y1.z, y1.w};
#pragma unroll
      for (int i = 0; i < 4; ++i)
#pragma unroll
        for (int j = 0; j < 8; ++j) acc[i][j] = fmaf(av[i], bv[j], acc[i][j]);
    }
    __syncthreads();
  }
#pragma unroll
  for (int i = 0; i < 4; ++i) {
    int row = bm + tm + i;
    float out[8];
#pragma unroll
    for (int j = 0; j < 8; ++j) {
      int col = bn + tn + j;
      float vv = acc[i][j];
      if (MODE == 1) vv *= csc1[col];
      if (MODE == 2) vv = vv * csc1[col] + csc2[col] * wadd[(size_t)row * HID + col];
      out[j] = vv;
    }
    *(float4*)(C + (size_t)row * ldc + bn + tn) = *(float4*)&out[0];
    *(float4*)(C + (size_t)row * ldc + bn + tn + 4) = *(float4*)&out[4];
  }
}

// ---------------- augmented-matrix setup ----------------
__global__ __launch_bounds__(256) void k_setup(const float* __restrict__ dq1, const float* __restrict__ rhs,
                                               float* __restrict__ Ag) {
  int idx = blockIdx.x * 256 + threadIdx.x;  // 1024*1088
  int r = idx / LDA, c = idx % LDA;
  float v = (c < 1024) ? dq1[(size_t)r * 1024 + c] : (c == 1024 ? rhs[r] : 0.f);
  Ag[idx] = v;
}

// ---------------- blocked LU (NB=64, no pivoting), rhs as augmented col ----------------

__global__ __launch_bounds__(256) void lu_diag(float* __restrict__ Ag, int o) {
  __shared__ float T[64][65];
  int t = threadIdx.x;
  for (int idx = t; idx < 4096; idx += 256) {
    int r = idx >> 6, c = idx & 63;
    T[r][c] = Ag[(size_t)(o + r) * LDA + o + c];
  }
  __syncthreads();
  int r = t & 63, cg = t >> 6;
  for (int kk = 0; kk < 63; ++kk) {
    if (cg == 0 && r > kk) T[r][kk] /= T[kk][kk];
    __syncthreads();
    float l = (r > kk) ? T[r][kk] : 0.f;
    int c0 = cg * 16;
#pragma unroll
    for (int j = 0; j < 16; ++j) {
      int c = c0 + j;
      if (r > kk && c > kk) T[r][c] = fmaf(-l, T[kk][c], T[r][c]);
    }
    __syncthreads();
  }
  for (int idx = t; idx < 4096; idx += 256) {
    int rr = idx >> 6, c = idx & 63;
    Ag[(size_t)(o + rr) * LDA + o + c] = T[rr][c];
  }
}

__global__ __launch_bounds__(256) void lu_panel(float* __restrict__ Ag, int o, int NU) {
  __shared__ float Ds[64][65];
  __shared__ float Xs[64][65];
  __shared__ float rp[64];
  int t = threadIdx.x;
  bool isU = (int)blockIdx.x < NU;
  size_t tb;
  if (isU) tb = (size_t)o * LDA + (o + 64 + (int)blockIdx.x * 64);
  else     tb = (size_t)(o + 64 + ((int)blockIdx.x - NU) * 64) * LDA + o;
  for (int idx = t; idx < 4096; idx += 256) {
    int r = idx >> 6, c = idx & 63;
    Ds[r][c] = Ag[(size_t)(o + r) * LDA + o + c];
    Xs[r][c] = Ag[tb + (size_t)r * LDA + c];
  }
  __syncthreads();
  if (!isU && t < 64) rp[t] = 1.f / Ds[t][t];
  __syncthreads();
  if (isU) {
    int cl = t & 63, rg = t >> 6;
    for (int kk = 0; kk < 63; ++kk) {
      float xk = Xs[kk][cl];
      int i0 = rg * 16;
#pragma unroll
      for (int j = 0; j < 16; ++j) {
        int i = i0 + j;
        if (i > kk) Xs[i][cl] = fmaf(-Ds[i][kk], xk, Xs[i][cl]);
      }
      __syncthreads();
    }
  } else {
    int r = t & 63, cg = t >> 6;
    for (int kk = 0; kk < 64; ++kk) {
      if (cg == (kk >> 4)) Xs[r][kk] *= rp[kk];
      __syncthreads();
      float vk = Xs[r][kk];
      int c0 = cg * 16;
#pragma unroll
      for (int j = 0; j < 16; ++j) {
        int m = c0 + j;
        if (m > kk) Xs[r][m] = fmaf(-vk, Ds[kk][m], Xs[r][m]);
      }
      __syncthreads();
    }
  }
  __syncthreads();
  for (int idx = t; idx < 4096; idx += 256) {
    int r = idx >> 6, c = idx & 63;
    Ag[tb + (size_t)r * LDA + c] = Xs[r][c];
  }
}

__global__ __launch_bounds__(256) void lu_schur(float* __restrict__ Ag, int o) {
  __shared__ float Ls[64][65];
  __shared__ float Us[64][65];
  int t = threadIdx.x;
  int c0 = o + 64 + blockIdx.x * 64;
  int r0 = o + 64 + blockIdx.y * 64;
  for (int idx = t; idx < 4096; idx += 256) {
    int r = idx >> 6, q = idx & 63;
    Ls[q][r] = Ag[(size_t)(r0 + r) * LDA + o + q];
    Us[r][q] = Ag[(size_t)(o + r) * LDA + c0 + q];
  }
  __syncthreads();
  int tm = (t >> 4) * 4, tn = (t & 15) * 4;
  float acc[4][4];
#pragma unroll
  for (int i = 0; i < 4; ++i)
#pragma unroll
    for (int j = 0; j < 4; ++j) acc[i][j] = 0.f;
#pragma unroll 8
  for (int kk = 0; kk < 64; ++kk) {
    float a[4], b[4];
#pragma unroll
    for (int i = 0; i < 4; ++i) a[i] = Ls[kk][tm + i];
#pragma unroll
    for (int j = 0; j < 4; ++j) b[j] = Us[kk][tn + j];
#pragma unroll
    for (int i = 0; i < 4; ++i)
#pragma unroll
      for (int j = 0; j < 4; ++j) acc[i][j] = fmaf(a[i], b[j], acc[i][j]);
  }
#pragma unroll
  for (int i = 0; i < 4; ++i)
#pragma unroll
    for (int j = 0; j < 4; ++j) Ag[(size_t)(r0 + tm + i) * LDA + c0 + tn + j] -= acc[i][j];
}

// ---------------- whole-triangular-solve kernels (single block) ----------------

__global__ __launch_bounds__(256) void bs_all(const float* __restrict__ Ag, float* __restrict__ yb) {
  __shared__ float ys[1024];
  __shared__ float Td[64][65];
  int t = threadIdx.x;
  for (int i = t; i < 1024; i += 256) ys[i] = Ag[(size_t)i * LDA + 1024];
  __syncthreads();
  for (int kb = 15; kb >= 0; --kb) {
    int o = kb * 64;
    for (int idx = t; idx < 4096; idx += 256) {
      int r = idx >> 6, c = idx & 63;
      Td[r][c] = Ag[(size_t)(o + r) * LDA + o + c];
    }
    __syncthreads();
    if (t < 64) {
      float yv = ys[o + t];
      float rpv = 1.f / Td[t][t];
#pragma unroll 16
      for (int kk = 63; kk >= 0; --kk) {
        float xk = __shfl(yv * rpv, kk, 64);
        if (t == kk) yv = xk;
        else if (t < kk) yv = fmaf(-Td[t][kk], xk, yv);
      }
      ys[o + t] = yv;
    }
    __syncthreads();
    if (o > 0) {
      int c = t & 63, wg = t >> 6;
      float yc = ys[o + c];
      for (int rr = wg; rr < o; rr += 16) {
        float p0 = Ag[(size_t)rr * LDA + o + c] * yc;
        float p1 = Ag[(size_t)(rr + 4) * LDA + o + c] * yc;
        float p2 = Ag[(size_t)(rr + 8) * LDA + o + c] * yc;
        float p3 = Ag[(size_t)(rr + 12) * LDA + o + c] * yc;
        p0 = wred(p0); p1 = wred(p1); p2 = wred(p2); p3 = wred(p3);
        if (c == 0) { ys[rr] -= p0; ys[rr + 4] -= p1; ys[rr + 8] -= p2; ys[rr + 12] -= p3; }
      }
      __syncthreads();
    }
  }
  for (int i = t; i < 1024; i += 256) yb[i] = ys[i];
}

__global__ __launch_bounds__(256) void k_resid(const float* __restrict__ dq1, const float* __restrict__ x0,
                                               const float* __restrict__ rhs, float* __restrict__ rv) {
  int w = threadIdx.x >> 6, lane = threadIdx.x & 63;
  int row = blockIdx.x * 4 + w;
  const float* p = dq1 + (size_t)row * 1024;
  float acc = 0.f;
  for (int j = lane; j < 1024; j += 64) acc = fmaf(p[j], x0[j], acc);
  acc = wred(acc);
  if (lane == 0) rv[row] = rhs[row] - acc;
}

__global__ __launch_bounds__(256) void fsbs_all(const float* __restrict__ Ag, const float* __restrict__ rv,
                                                const float* __restrict__ yb, float* __restrict__ out) {
  __shared__ float ys[1024];
  __shared__ float Td[64][65];
  int t = threadIdx.x;
  for (int i = t; i < 1024; i += 256) ys[i] = rv[i];
  __syncthreads();
  // forward substitution (unit lower)
  for (int kb = 0; kb < 16; ++kb) {
    int o = kb * 64;
    for (int idx = t; idx < 4096; idx += 256) {
      int r = idx >> 6, c = idx & 63;
      Td[r][c] = Ag[(size_t)(o + r) * LDA + o + c];
    }
    __syncthreads();
    if (t < 64) {
      float yv = ys[o + t];
#pragma unroll 16
      for (int kk = 0; kk < 63; ++kk) {
        float xk = __shfl(yv, kk, 64);
        if (t > kk) yv = fmaf(-Td[t][kk], xk, yv);
      }
      ys[o + t] = yv;
    }
    __syncthreads();
    if (o < 960) {
      int c = t & 63, wg = t >> 6;
      float yc = ys[o + c];
      for (int rr = o + 64 + wg; rr < 1024; rr += 16) {
        float p0 = Ag[(size_t)rr * LDA + o + c] * yc;
        float p1 = Ag[(size_t)(rr + 4) * LDA + o + c] * yc;
        float p2 = Ag[(size_t)(rr + 8) * LDA + o + c] * yc;
        float p3 = Ag[(size_t)(rr + 12) * LDA + o + c] * yc;
        p0 = wred(p0); p1 = wred(p1); p2 = wred(p2); p3 = wred(p3);
        if (c == 0) { ys[rr] -= p0; ys[rr + 4] -= p1; ys[rr + 8] -= p2; ys[rr + 12] -= p3; }
      }
      __syncthreads();
    }
  }
  // back substitution
  for (int kb = 15; kb >= 0; --kb) {
    int o = kb * 64;
    for (int idx = t; idx < 4096; idx += 256) {
      int r = idx >> 6, c = idx & 63;
      Td[r][c] = Ag[(size_t)(o + r) * LDA + o + c];
    }
    __syncthreads();
    if (t < 64) {
      float yv = ys[o + t];
      float rpv = 1.f / Td[t][t];
#pragma unroll 16
      for (int kk = 63; kk >= 0; --kk) {
        float xk = __shfl(yv * rpv, kk, 64);
        if (t == kk) yv = xk;
        else if (t < kk) yv = fmaf(-Td[t][kk], xk, yv);
      }
      ys[o + t] = yv;
    }
    __syncthreads();
    if (o > 0) {
      int c = t & 63, wg = t >> 6;
      float yc = ys[o + c];
      for (int rr = wg; rr < o; rr += 16) {
        float p0 = Ag[(size_t)rr * LDA + o + c] * yc;
        float p1 = Ag[(size_t)(rr + 4) * LDA + o + c] * yc;
        float p2 = Ag[(size_t)(rr + 8) * LDA + o + c] * yc;
        float p3 = Ag[(size_t)(rr + 12) * LDA + o + c] * yc;
        p0 = wred(p0); p1 = wred(p1); p2 = wred(p2); p3 = wred(p3);
        if (c == 0) { ys[rr] -= p0; ys[rr + 4] -= p1; ys[rr + 8] -= p2; ys[rr + 12] -= p3; }
      }
      __syncthreads();
    }
  }
  for (int i = t; i < 1024; i += 256) out[i] = yb[i] + ys[i];
}

// ---------------- launcher ----------------

extern "C" void kernel_launch(void* const* d_in, const int* in_sizes, int n_in, void* d_out,
                              int out_size, void* d_ws, size_t ws_size, hipStream_t stream) {
  const float* x  = (const float*)d_in[0];
  const float* W1 = (const float*)d_in[1];
  const float* b1 = (const float*)d_in[2];
  const float* W2 = (const float*)d_in[3];
  const float* b2 = (const float*)d_in[4];
  const float* W3 = (const float*)d_in[5];
  float* out = (float*)d_out;
  float* ws = (float*)d_ws;

  // workspace layout (floats); same as round 5
  float* h1  = ws + 0;
  float* s1  = ws + 4096;
  float* s1p = ws + 8192;
  float* d1  = ws + 12288;
  float* g2  = ws + 16384;
  float* d2  = ws + 20480;
  float* g1  = ws + 24576;
  float* vv  = ws + 28672;
  float* dq0 = ws + 32768;
  float* rhs = ws + 33792;
  float* yb  = ws + 34816;
  float* rv  = ws + 35840;
  float* Bbs = ws + 65536;
  float* QT  = Bbs + (size_t)1024 * HID;
  float* Ag  = QT + (size_t)1024 * HID;
  float* dq1 = Ag + (size_t)1024 * LDA;

  // deterministic-reduction partial buffers, aliased into Ag (dead until k_setup)
  float* zp1 = Ag;            //  8 x 4096
  float* zp2 = Ag + 32768;    // 16 x 4096
  float* vp  = Ag + 98304;    //  8 x 4096

  const float* W1b = W1 + (size_t)NH * HID;

  // forward + backward vectors (no atomics anywhere)
  k_z1p<<<dim3(16, 8), 256, 0, stream>>>(x, W1, zp1);
  k_act1<<<16, 256, 0, stream>>>(zp1, b1, h1, s1, s1p);
  k_z2p<<<dim3(16, 16), 256, 0, stream>>>(h1, W2, zp2);
  k_act2<<<16, 256, 0, stream>>>(zp2, b2, W3, g2, d2);
  k_u<<<1024, 256, 0, stream>>>(W2, g2, s1, s1p, g1, d1);
  k_dq0<<<256, 256, 0, stream>>>(W1, g1, dq0);

  // Hessian blocks: Bbs = (W1b*s1)@W2 * D2 ; QT = s1*(Bbs@W2^T) + d1*W1b ; dq1 = W1b@QT^T
  // (retiled to 128x64: 512 / 512 / 128 blocks)
  gemm_k<false, 1><<<dim3(64, 8), 256, 0, stream>>>(W1b, HID, W2, HID, Bbs, HID, HID, s1, d2, nullptr, nullptr);
  gemm_k<true, 2><<<dim3(64, 8), 256, 0, stream>>>(Bbs, HID, W2, HID, QT, HID, HID, nullptr, s1, d1, W1b);
  gemm_k<true, 0><<<dim3(16, 8), 256, 0, stream>>>(W1b, HID, QT, HID, dq1, 1024, HID, nullptr, nullptr, nullptr, nullptr);

  // rhs = dq0 - dq2 @ x[n:]  via vv = QT^T @ x[n:]
  k_vp<<<dim3(16, 8), 256, 0, stream>>>(QT, x, vp);
  k_vred<<<16, 256, 0, stream>>>(vp, vv);
  k_rhs<<<256, 256, 0, stream>>>(W1, vv, dq0, rhs);
  k_setup<<<(1024 * LDA) / 256, 256, 0, stream>>>(dq1, rhs, Ag);

  // blocked LU, rhs carried in augmented column
  for (int kb = 0; kb < 16; ++kb) {
    int o = kb * 64;
    int NU = 16 - kb;   // col tiles right of diag (incl rhs+pad tile)
    int NL = 15 - kb;   // row tiles below diag
    lu_diag<<<1, 256, 0, stream>>>(Ag, o);
    lu_panel<<<NU + NL, 256, 0, stream>>>(Ag, o, NU);
    if (NL > 0) lu_schur<<<dim3(NU, NL), 256, 0, stream>>>(Ag, o);
  }

  // solve + one iterative-refinement pass
  bs_all<<<1, 256, 0, stream>>>(Ag, yb);
  k_resid<<<256, 256, 0, stream>>>(dq1, yb, rhs, rv);
  fsbs_all<<<1, 256, 0, stream>>>(Ag, rv, yb, out);
}

// Round 7
// 3776.014 us; speedup vs baseline: 1.4087x; 1.2978x over previous
//
#include <hip/hip_runtime.h>
#include <cstddef>

#define HID 4096
#define NH 1024
#define LDA 1088   // augmented LU matrix: 1024 cols + rhs col + 63 pad cols

typedef short short8v __attribute__((ext_vector_type(8)));
typedef short short4v __attribute__((ext_vector_type(4)));
typedef float f32x4 __attribute__((ext_vector_type(4)));

__device__ __forceinline__ float wred(float a) {
#pragma unroll
  for (int off = 32; off > 0; off >>= 1) a += __shfl_down(a, off);
  return a;
}

// ---------------- bf16 split helpers (RNE) ----------------
__device__ __forceinline__ unsigned short bf16rne(float x) {
  unsigned b = __float_as_uint(x);
  unsigned r = b + 0x7FFFu + ((b >> 16) & 1u);
  return (unsigned short)(r >> 16);
}
__device__ __forceinline__ void split1(float x, unsigned short& h, unsigned short& l) {
  h = bf16rne(x);
  float hf = __uint_as_float((unsigned)h << 16);
  l = bf16rne(x - hf);
}
__device__ __forceinline__ void split4(float4 v, short4v& hv, short4v& lv) {
  unsigned short h, l;
  split1(v.x, h, l); hv[0] = (short)h; lv[0] = (short)l;
  split1(v.y, h, l); hv[1] = (short)h; lv[1] = (short)l;
  split1(v.z, h, l); hv[2] = (short)h; lv[2] = (short)l;
  split1(v.w, h, l); hv[3] = (short)h; lv[3] = (short)l;
}

// ---------------- forward / backward vector pipeline (deterministic: no atomics) ----------------

__global__ __launch_bounds__(256) void k_z1p(const float* __restrict__ x, const float* __restrict__ W1,
                                             float* __restrict__ zp1) {
  int k = blockIdx.x * 256 + threadIdx.x;
  int i0 = blockIdx.y * 256;
  float acc = 0.f;
  for (int i = i0; i < i0 + 256; ++i) acc = fmaf(x[i], W1[(size_t)i * HID + k], acc);
  zp1[(size_t)blockIdx.y * HID + k] = acc;
}

__global__ __launch_bounds__(256) void k_act1(const float* __restrict__ zp1, const float* __restrict__ b1,
                                              float* __restrict__ h1, float* __restrict__ s1,
                                              float* __restrict__ s1p) {
  int k = blockIdx.x * 256 + threadIdx.x;
  float z = b1[k];
#pragma unroll
  for (int j = 0; j < 8; ++j) z += zp1[(size_t)j * HID + k];
  float sg = 1.f / (1.f + expf(-z));
  h1[k] = (z > 20.f) ? z : log1pf(expf(z));
  s1[k] = sg;
  s1p[k] = sg * (1.f - sg);
}

__global__ __launch_bounds__(256) void k_z2p(const float* __restrict__ h1, const float* __restrict__ W2,
                                             float* __restrict__ zp2) {
  int j = blockIdx.x * 256 + threadIdx.x;
  int i0 = blockIdx.y * 256;
  float acc = 0.f;
  for (int i = i0; i < i0 + 256; ++i) acc = fmaf(h1[i], W2[(size_t)i * HID + j], acc);
  zp2[(size_t)blockIdx.y * HID + j] = acc;
}

__global__ __launch_bounds__(256) void k_act2(const float* __restrict__ zp2, const float* __restrict__ b2,
                                              const float* __restrict__ w3, float* __restrict__ g2,
                                              float* __restrict__ d2) {
  int j = blockIdx.x * 256 + threadIdx.x;
  float z = b2[j];
#pragma unroll
  for (int q = 0; q < 16; ++q) z += zp2[(size_t)q * HID + j];
  float sg = 1.f / (1.f + expf(-z));
  float w = w3[j];
  g2[j] = sg * w;
  d2[j] = sg * (1.f - sg) * w;
}

__global__ __launch_bounds__(256) void k_u(const float* __restrict__ W2, const float* __restrict__ g2,
                                           const float* __restrict__ s1, const float* __restrict__ s1p,
                                           float* __restrict__ g1, float* __restrict__ d1) {
  int w = threadIdx.x >> 6, lane = threadIdx.x & 63;
  int row = blockIdx.x * 4 + w;
  const float* p = W2 + (size_t)row * HID;
  float acc = 0.f;
  for (int j = lane; j < HID; j += 64) acc = fmaf(p[j], g2[j], acc);
  acc = wred(acc);
  if (lane == 0) {
    g1[row] = s1[row] * acc;
    d1[row] = s1p[row] * acc;
  }
}

__global__ __launch_bounds__(256) void k_dq0(const float* __restrict__ W1, const float* __restrict__ g1,
                                             float* __restrict__ dq0) {
  int w = threadIdx.x >> 6, lane = threadIdx.x & 63;
  int row = blockIdx.x * 4 + w;
  const float* p = W1 + (size_t)row * HID;
  float acc = 0.f;
  for (int k = lane; k < HID; k += 64) acc = fmaf(p[k], g1[k], acc);
  acc = wred(acc);
  if (lane == 0) dq0[row] = acc;
}

__global__ __launch_bounds__(256) void k_vp(const float* __restrict__ QT, const float* __restrict__ x,
                                            float* __restrict__ vp) {
  int l = blockIdx.x * 256 + threadIdx.x;
  int r0 = blockIdx.y * 128;
  float acc = 0.f;
  for (int r = r0; r < r0 + 128; ++r) acc = fmaf(QT[(size_t)r * HID + l], x[NH + r], acc);
  vp[(size_t)blockIdx.y * HID + l] = acc;
}

__global__ __launch_bounds__(256) void k_vred(const float* __restrict__ vp, float* __restrict__ vv) {
  int l = blockIdx.x * 256 + threadIdx.x;
  float a = 0.f;
#pragma unroll
  for (int j = 0; j < 8; ++j) a += vp[(size_t)j * HID + l];
  vv[l] = a;
}

__global__ __launch_bounds__(256) void k_rhs(const float* __restrict__ W1, const float* __restrict__ v,
                                             const float* __restrict__ dq0, float* __restrict__ rhs) {
  int w = threadIdx.x >> 6, lane = threadIdx.x & 63;
  int row = blockIdx.x * 4 + w;
  const float* p = W1 + (size_t)row * HID;
  float acc = 0.f;
  for (int l = lane; l < HID; l += 64) acc = fmaf(p[l], v[l], acc);
  acc = wred(acc);
  if (lane == 0) rhs[row] = dq0[row] - acc;
}

// ---------------- split-bf16 MFMA GEMM: 128x128 tile, BK=64, 4 waves (2x2), 4x4 MFMA tiles/wave ----
// C[m,n] = sum_k Ahat[m,k]*Bmat(k,n),  Bmat(k,n) = TRANSB ? B[n*ldb+k] : B[k*ldb+n]
// Each fp32 operand split hi+lo (bf16 RNE); 4 MFMA products (ll,hl,lh,hh) into one fp32 acc.
// MODE 0: C = acc ; MODE 1: A k-scaled by ks at staging, C = acc*csc1[col]
// MODE 2: C = acc*csc1[col] + csc2[col]*wadd[row*HID+col]
template <bool TRANSB, int MODE>
__global__ __launch_bounds__(256) void mfma_gemm(const float* __restrict__ A, int lda,
                                                 const float* __restrict__ B, int ldb,
                                                 float* __restrict__ C, int ldc, int K,
                                                 const float* __restrict__ ks,
                                                 const float* __restrict__ csc1,
                                                 const float* __restrict__ csc2,
                                                 const float* __restrict__ wadd) {
  // [k-half][row/col 128][32 + 8 pad] ; stride 80B keeps 16B-aligned fragments, ~2-way banks
  __shared__ unsigned short Ah[2][128][40] __attribute__((aligned(16)));
  __shared__ unsigned short Al[2][128][40] __attribute__((aligned(16)));
  __shared__ unsigned short Bh[2][128][40] __attribute__((aligned(16)));
  __shared__ unsigned short Bl[2][128][40] __attribute__((aligned(16)));

  const int tid = threadIdx.x;
  const int lane = tid & 63;
  const int wid = tid >> 6;
  const int wm = wid >> 1, wn = wid & 1;
  const int bm = blockIdx.y * 128, bn = blockIdx.x * 128;
  const int frow = lane & 15;
  const int kg = lane >> 4;

  f32x4 acc[4][4];
#pragma unroll
  for (int i = 0; i < 4; ++i)
#pragma unroll
    for (int j = 0; j < 4; ++j) acc[i][j] = (f32x4){0.f, 0.f, 0.f, 0.f};

  const int ar = tid >> 1;      // A row / B col (TRANSB)
  const int ah = tid & 1;       // k-half
  const int bcol = tid & 127;   // !TRANSB B staging
  const int bkh = tid >> 7;

  for (int k0 = 0; k0 < K; k0 += 64) {
    __syncthreads();
    {  // stage A (row-major [m][k])
      const float* Ap = A + (size_t)(bm + ar) * lda + (k0 + ah * 32);
#pragma unroll
      for (int i = 0; i < 8; ++i) {
        float4 v = *(const float4*)(Ap + i * 4);
        if (MODE == 1) {
          const float* kp = ks + k0 + ah * 32 + i * 4;
          v.x *= kp[0]; v.y *= kp[1]; v.z *= kp[2]; v.w *= kp[3];
        }
        short4v hv, lv;
        split4(v, hv, lv);
        *(short4v*)&Ah[ah][ar][i * 4] = hv;
        *(short4v*)&Al[ah][ar][i * 4] = lv;
      }
    }
    if (TRANSB) {  // B row-major [n][k] -> Bs[col][k] contiguous
      const float* Bp = B + (size_t)(bn + ar) * ldb + (k0 + ah * 32);
#pragma unroll
      for (int i = 0; i < 8; ++i) {
        float4 v = *(const float4*)(Bp + i * 4);
        short4v hv, lv;
        split4(v, hv, lv);
        *(short4v*)&Bh[ah][ar][i * 4] = hv;
        *(short4v*)&Bl[ah][ar][i * 4] = lv;
      }
    } else {  // B row-major [k][n] -> in-LDS transpose to Bs[col][k]
#pragma unroll
      for (int i = 0; i < 32; ++i) {
        float xv = B[(size_t)(k0 + bkh * 32 + i) * ldb + bn + bcol];
        unsigned short h, l;
        split1(xv, h, l);
        Bh[bkh][bcol][i] = h;
        Bl[bkh][bcol][i] = l;
      }
    }
    __syncthreads();
#pragma unroll
    for (int kk = 0; kk < 2; ++kk) {
      short8v a_h[4], a_l[4], b_h[4], b_l[4];
#pragma unroll
      for (int mt = 0; mt < 4; ++mt) {
        int r = wm * 64 + mt * 16 + frow;
        a_h[mt] = *(const short8v*)&Ah[kk][r][kg * 8];
        a_l[mt] = *(const short8v*)&Al[kk][r][kg * 8];
      }
#pragma unroll
      for (int nt = 0; nt < 4; ++nt) {
        int c = wn * 64 + nt * 16 + frow;
        b_h[nt] = *(const short8v*)&Bh[kk][c][kg * 8];
        b_l[nt] = *(const short8v*)&Bl[kk][c][kg * 8];
      }
#pragma unroll
      for (int mt = 0; mt < 4; ++mt)
#pragma unroll
        for (int nt = 0; nt < 4; ++nt) {
          acc[mt][nt] = __builtin_amdgcn_mfma_f32_16x16x32_bf16(a_l[mt], b_l[nt], acc[mt][nt], 0, 0, 0);
          acc[mt][nt] = __builtin_amdgcn_mfma_f32_16x16x32_bf16(a_h[mt], b_l[nt], acc[mt][nt], 0, 0, 0);
          acc[mt][nt] = __builtin_amdgcn_mfma_f32_16x16x32_bf16(a_l[mt], b_h[nt], acc[mt][nt], 0, 0, 0);
          acc[mt][nt] = __builtin_amdgcn_mfma_f32_16x16x32_bf16(a_h[mt], b_h[nt], acc[mt][nt], 0, 0, 0);
        }
    }
  }
  // epilogue: C/D layout col=lane&15, row=(lane>>4)*4+j (verified m89)
#pragma unroll
  for (int mt = 0; mt < 4; ++mt)
#pragma unroll
    for (int nt = 0; nt < 4; ++nt) {
      int col = bn + wn * 64 + nt * 16 + frow;
      float c1 = (MODE >= 1) ? csc1[col] : 0.f;
      float c2 = (MODE == 2) ? csc2[col] : 0.f;
#pragma unroll
      for (int j = 0; j < 4; ++j) {
        int row = bm + wm * 64 + mt * 16 + kg * 4 + j;
        float v = acc[mt][nt][j];
        if (MODE == 1) v *= c1;
        if (MODE == 2) v = v * c1 + c2 * wadd[(size_t)row * HID + col];
        C[(size_t)row * ldc + col] = v;
      }
    }
}

// ---------------- augmented-matrix setup ----------------
__global__ __launch_bounds__(256) void k_setup(const float* __restrict__ dq1, const float* __restrict__ rhs,
                                               float* __restrict__ Ag) {
  int idx = blockIdx.x * 256 + threadIdx.x;  // 1024*1088
  int r = idx / LDA, c = idx % LDA;
  float v = (c < 1024) ? dq1[(size_t)r * 1024 + c] : (c == 1024 ? rhs[r] : 0.f);
  Ag[idx] = v;
}

// ---------------- blocked LU (NB=64, no pivoting), rhs as augmented col ----------------

__global__ __launch_bounds__(256) void lu_diag(float* __restrict__ Ag, int o) {
  __shared__ float T[64][65];
  int t = threadIdx.x;
  for (int idx = t; idx < 4096; idx += 256) {
    int r = idx >> 6, c = idx & 63;
    T[r][c] = Ag[(size_t)(o + r) * LDA + o + c];
  }
  __syncthreads();
  int r = t & 63, cg = t >> 6;
  for (int kk = 0; kk < 63; ++kk) {
    if (cg == 0 && r > kk) T[r][kk] /= T[kk][kk];
    __syncthreads();
    float l = (r > kk) ? T[r][kk] : 0.f;
    int c0 = cg * 16;
#pragma unroll
    for (int j = 0; j < 16; ++j) {
      int c = c0 + j;
      if (r > kk && c > kk) T[r][c] = fmaf(-l, T[kk][c], T[r][c]);
    }
    __syncthreads();
  }
  for (int idx = t; idx < 4096; idx += 256) {
    int rr = idx >> 6, c = idx & 63;
    Ag[(size_t)(o + rr) * LDA + o + c] = T[rr][c];
  }
}

__global__ __launch_bounds__(256) void lu_panel(float* __restrict__ Ag, int o, int NU) {
  __shared__ float Ds[64][65];
  __shared__ float Xs[64][65];
  __shared__ float rp[64];
  int t = threadIdx.x;
  bool isU = (int)blockIdx.x < NU;
  size_t tb;
  if (isU) tb = (size_t)o * LDA + (o + 64 + (int)blockIdx.x * 64);
  else     tb = (size_t)(o + 64 + ((int)blockIdx.x - NU) * 64) * LDA + o;
  for (int idx = t; idx < 4096; idx += 256) {
    int r = idx >> 6, c = idx & 63;
    Ds[r][c] = Ag[(size_t)(o + r) * LDA + o + c];
    Xs[r][c] = Ag[tb + (size_t)r * LDA + c];
  }
  __syncthreads();
  if (!isU && t < 64) rp[t] = 1.f / Ds[t][t];
  __syncthreads();
  if (isU) {
    int cl = t & 63, rg = t >> 6;
    for (int kk = 0; kk < 63; ++kk) {
      float xk = Xs[kk][cl];
      int i0 = rg * 16;
#pragma unroll
      for (int j = 0; j < 16; ++j) {
        int i = i0 + j;
        if (i > kk) Xs[i][cl] = fmaf(-Ds[i][kk], xk, Xs[i][cl]);
      }
      __syncthreads();
    }
  } else {
    int r = t & 63, cg = t >> 6;
    for (int kk = 0; kk < 64; ++kk) {
      if (cg == (kk >> 4)) Xs[r][kk] *= rp[kk];
      __syncthreads();
      float vk = Xs[r][kk];
      int c0 = cg * 16;
#pragma unroll
      for (int j = 0; j < 16; ++j) {
        int m = c0 + j;
        if (m > kk) Xs[r][m] = fmaf(-vk, Ds[kk][m], Xs[r][m]);
      }
      __syncthreads();
    }
  }
  __syncthreads();
  for (int idx = t; idx < 4096; idx += 256) {
    int r = idx >> 6, c = idx & 63;
    Ag[tb + (size_t)r * LDA + c] = Xs[r][c];
  }
}

__global__ __launch_bounds__(256) void lu_schur(float* __restrict__ Ag, int o) {
  __shared__ float Ls[64][65];
  __shared__ float Us[64][65];
  int t = threadIdx.x;
  int c0 = o + 64 + blockIdx.x * 64;
  int r0 = o + 64 + blockIdx.y * 64;
  for (int idx = t; idx < 4096; idx += 256) {
    int r = idx >> 6, q = idx & 63;
    Ls[q][r] = Ag[(size_t)(r0 + r) * LDA + o + q];
    Us[r][q] = Ag[(size_t)(o + r) * LDA + c0 + q];
  }
  __syncthreads();
  int tm = (t >> 4) * 4, tn = (t & 15) * 4;
  float acc[4][4];
#pragma unroll
  for (int i = 0; i < 4; ++i)
#pragma unroll
    for (int j = 0; j < 4; ++j) acc[i][j] = 0.f;
#pragma unroll 8
  for (int kk = 0; kk < 64; ++kk) {
    float a[4], b[4];
#pragma unroll
    for (int i = 0; i < 4; ++i) a[i] = Ls[kk][tm + i];
#pragma unroll
    for (int j = 0; j < 4; ++j) b[j] = Us[kk][tn + j];
#pragma unroll
    for (int i = 0; i < 4; ++i)
#pragma unroll
      for (int j = 0; j < 4; ++j) acc[i][j] = fmaf(a[i], b[j], acc[i][j]);
  }
#pragma unroll
  for (int i = 0; i < 4; ++i)
#pragma unroll
    for (int j = 0; j < 4; ++j) Ag[(size_t)(r0 + tm + i) * LDA + c0 + tn + j] -= acc[i][j];
}

// ---------------- whole-triangular-solve kernels (single block, 1024 threads) ----------------

__global__ __launch_bounds__(1024) void bs_all(const float* __restrict__ Ag, float* __restrict__ yb) {
  __shared__ float ys[1024];
  __shared__ float Td[64][65];
  int t = threadIdx.x;
  ys[t] = Ag[(size_t)t * LDA + 1024];
  __syncthreads();
  for (int kb = 15; kb >= 0; --kb) {
    int o = kb * 64;
    for (int idx = t; idx < 4096; idx += 1024) {
      int r = idx >> 6, c = idx & 63;
      Td[r][c] = Ag[(size_t)(o + r) * LDA + o + c];
    }
    __syncthreads();
    if (t < 64) {
      float yv = ys[o + t];
      float rpv = 1.f / Td[t][t];
#pragma unroll 16
      for (int kk = 63; kk >= 0; --kk) {
        float xk = __shfl(yv * rpv, kk, 64);
        if (t == kk) yv = xk;
        else if (t < kk) yv = fmaf(-Td[t][kk], xk, yv);
      }
      ys[o + t] = yv;
    }
    __syncthreads();
    if (o > 0) {
      int c = t & 63, wg = t >> 6;  // 16 waves
      float yc = ys[o + c];
      for (int rr = wg; rr < o; rr += 64) {
        float p0 = Ag[(size_t)rr * LDA + o + c] * yc;
        float p1 = Ag[(size_t)(rr + 16) * LDA + o + c] * yc;
        float p2 = Ag[(size_t)(rr + 32) * LDA + o + c] * yc;
        float p3 = Ag[(size_t)(rr + 48) * LDA + o + c] * yc;
        p0 = wred(p0); p1 = wred(p1); p2 = wred(p2); p3 = wred(p3);
        if (c == 0) { ys[rr] -= p0; ys[rr + 16] -= p1; ys[rr + 32] -= p2; ys[rr + 48] -= p3; }
      }
      __syncthreads();
    }
  }
  yb[t] = ys[t];
}

__global__ __launch_bounds__(256) void k_resid(const float* __restrict__ dq1, const float* __restrict__ x0,
                                               const float* __restrict__ rhs, float* __restrict__ rv) {
  int w = threadIdx.x >> 6, lane = threadIdx.x & 63;
  int row = blockIdx.x * 4 + w;
  const float* p = dq1 + (size_t)row * 1024;
  float acc = 0.f;
  for (int j = lane; j < 1024; j += 64) acc = fmaf(p[j], x0[j], acc);
  acc = wred(acc);
  if (lane == 0) rv[row] = rhs[row] - acc;
}

__global__ __launch_bounds__(1024) void fsbs_all(const float* __restrict__ Ag, const float* __restrict__ rv,
                                                 const float* __restrict__ yb, float* __restrict__ out) {
  __shared__ float ys[1024];
  __shared__ float Td[64][65];
  int t = threadIdx.x;
  ys[t] = rv[t];
  __syncthreads();
  // forward substitution (unit lower)
  for (int kb = 0; kb < 16; ++kb) {
    int o = kb * 64;
    for (int idx = t; idx < 4096; idx += 1024) {
      int r = idx >> 6, c = idx & 63;
      Td[r][c] = Ag[(size_t)(o + r) * LDA + o + c];
    }
    __syncthreads();
    if (t < 64) {
      float yv = ys[o + t];
#pragma unroll 16
      for (int kk = 0; kk < 63; ++kk) {
        float xk = __shfl(yv, kk, 64);
        if (t > kk) yv = fmaf(-Td[t][kk], xk, yv);
      }
      ys[o + t] = yv;
    }
    __syncthreads();
    if (o < 960) {
      int c = t & 63, wg = t >> 6;
      float yc = ys[o + c];
      for (int rr = o + 64 + wg; rr < 1024; rr += 64) {
        float p0 = Ag[(size_t)rr * LDA + o + c] * yc;
        float p1 = Ag[(size_t)(rr + 16) * LDA + o + c] * yc;
        float p2 = Ag[(size_t)(rr + 32) * LDA + o + c] * yc;
        float p3 = Ag[(size_t)(rr + 48) * LDA + o + c] * yc;
        p0 = wred(p0); p1 = wred(p1); p2 = wred(p2); p3 = wred(p3);
        if (c == 0) { ys[rr] -= p0; ys[rr + 16] -= p1; ys[rr + 32] -= p2; ys[rr + 48] -= p3; }
      }
      __syncthreads();
    }
  }
  // back substitution
  for (int kb = 15; kb >= 0; --kb) {
    int o = kb * 64;
    for (int idx = t; idx < 4096; idx += 1024) {
      int r = idx >> 6, c = idx & 63;
      Td[r][c] = Ag[(size_t)(o + r) * LDA + o + c];
    }
    __syncthreads();
    if (t < 64) {
      float yv = ys[o + t];
      float rpv = 1.f / Td[t][t];
#pragma unroll 16
      for (int kk = 63; kk >= 0; --kk) {
        float xk = __shfl(yv * rpv, kk, 64);
        if (t == kk) yv = xk;
        else if (t < kk) yv = fmaf(-Td[t][kk], xk, yv);
      }
      ys[o + t] = yv;
    }
    __syncthreads();
    if (o > 0) {
      int c = t & 63, wg = t >> 6;
      float yc = ys[o + c];
      for (int rr = wg; rr < o; rr += 64) {
        float p0 = Ag[(size_t)rr * LDA + o + c] * yc;
        float p1 = Ag[(size_t)(rr + 16) * LDA + o + c] * yc;
        float p2 = Ag[(size_t)(rr + 32) * LDA + o + c] * yc;
        float p3 = Ag[(size_t)(rr + 48) * LDA + o + c] * yc;
        p0 = wred(p0); p1 = wred(p1); p2 = wred(p2); p3 = wred(p3);
        if (c == 0) { ys[rr] -= p0; ys[rr + 16] -= p1; ys[rr + 32] -= p2; ys[rr + 48] -= p3; }
      }
      __syncthreads();
    }
  }
  out[t] = yb[t] + ys[t];
}

// ---------------- launcher ----------------

extern "C" void kernel_launch(void* const* d_in, const int* in_sizes, int n_in, void* d_out,
                              int out_size, void* d_ws, size_t ws_size, hipStream_t stream) {
  const float* x  = (const float*)d_in[0];
  const float* W1 = (const float*)d_in[1];
  const float* b1 = (const float*)d_in[2];
  const float* W2 = (const float*)d_in[3];
  const float* b2 = (const float*)d_in[4];
  const float* W3 = (const float*)d_in[5];
  float* out = (float*)d_out;
  float* ws = (float*)d_ws;

  // workspace layout (floats); same high-water as round 5/6 (~40.5 MiB)
  float* h1  = ws + 0;
  float* s1  = ws + 4096;
  float* s1p = ws + 8192;
  float* d1  = ws + 12288;
  float* g2  = ws + 16384;
  float* d2  = ws + 20480;
  float* g1  = ws + 24576;
  float* vv  = ws + 28672;
  float* dq0 = ws + 32768;
  float* rhs = ws + 33792;
  float* yb  = ws + 34816;
  float* rv  = ws + 35840;
  float* Bbs = ws + 65536;
  float* QT  = Bbs + (size_t)1024 * HID;
  float* Ag  = QT + (size_t)1024 * HID;
  float* dq1 = Ag + (size_t)1024 * LDA;

  // deterministic-reduction partial buffers, aliased into Ag (dead until k_setup)
  float* zp1 = Ag;            //  8 x 4096
  float* zp2 = Ag + 32768;    // 16 x 4096
  float* vp  = Ag + 98304;    //  8 x 4096

  const float* W1b = W1 + (size_t)NH * HID;

  // forward + backward vectors (no atomics anywhere)
  k_z1p<<<dim3(16, 8), 256, 0, stream>>>(x, W1, zp1);
  k_act1<<<16, 256, 0, stream>>>(zp1, b1, h1, s1, s1p);
  k_z2p<<<dim3(16, 16), 256, 0, stream>>>(h1, W2, zp2);
  k_act2<<<16, 256, 0, stream>>>(zp2, b2, W3, g2, d2);
  k_u<<<1024, 256, 0, stream>>>(W2, g2, s1, s1p, g1, d1);
  k_dq0<<<256, 256, 0, stream>>>(W1, g1, dq0);

  // Hessian blocks via split-bf16 MFMA:
  // G1: Bbs = [(W1b *k s1) @ W2] *col d2
  mfma_gemm<false, 1><<<dim3(32, 8), 256, 0, stream>>>(
      W1b, HID, W2, HID, Bbs, HID, HID, s1, d2, nullptr, nullptr);
  // G2: QT = s1*col (Bbs @ W2^T) + d1*col W1b
  mfma_gemm<true, 2><<<dim3(32, 8), 256, 0, stream>>>(
      Bbs, HID, W2, HID, QT, HID, HID, nullptr, s1, d1, W1b);
  // G3: dq1 = W1b @ QT^T
  mfma_gemm<true, 0><<<dim3(8, 8), 256, 0, stream>>>(
      W1b, HID, QT, HID, dq1, 1024, HID, nullptr, nullptr, nullptr, nullptr);

  // rhs = dq0 - dq2 @ x[n:]  via vv = QT^T @ x[n:]
  k_vp<<<dim3(16, 8), 256, 0, stream>>>(QT, x, vp);
  k_vred<<<16, 256, 0, stream>>>(vp, vv);
  k_rhs<<<256, 256, 0, stream>>>(W1, vv, dq0, rhs);
  k_setup<<<(1024 * LDA) / 256, 256, 0, stream>>>(dq1, rhs, Ag);

  // blocked LU, rhs carried in augmented column
  for (int kb = 0; kb < 16; ++kb) {
    int o = kb * 64;
    int NU = 16 - kb;   // col tiles right of diag (incl rhs+pad tile)
    int NL = 15 - kb;   // row tiles below diag
    lu_diag<<<1, 256, 0, stream>>>(Ag, o);
    lu_panel<<<NU + NL, 256, 0, stream>>>(Ag, o, NU);
    if (NL > 0) lu_schur<<<dim3(NU, NL), 256, 0, stream>>>(Ag, o);
  }

  // solve + one iterative-refinement pass
  bs_all<<<1, 1024, 0, stream>>>(Ag, yb);
  k_resid<<<256, 256, 0, stream>>>(dq1, yb, rhs, rv);
  fsbs_all<<<1, 1024, 0, stream>>>(Ag, rv, yb, out);
}

// Round 8
// 3487.505 us; speedup vs baseline: 1.5252x; 1.0827x over previous
//
#include <hip/hip_runtime.h>
#include <cstddef>

#define HID 4096
#define NH 1024
#define LDA 1088   // augmented LU matrix: 1024 cols + rhs col + 63 pad cols

typedef short short8v __attribute__((ext_vector_type(8)));
typedef short short4v __attribute__((ext_vector_type(4)));
typedef float f32x4 __attribute__((ext_vector_type(4)));

__device__ __forceinline__ float wred(float a) {
#pragma unroll
  for (int off = 32; off > 0; off >>= 1) a += __shfl_down(a, off);
  return a;
}

// ---------------- bf16 split helpers (RNE) ----------------
__device__ __forceinline__ unsigned short bf16rne(float x) {
  unsigned b = __float_as_uint(x);
  unsigned r = b + 0x7FFFu + ((b >> 16) & 1u);
  return (unsigned short)(r >> 16);
}
__device__ __forceinline__ void split1(float x, unsigned short& h, unsigned short& l) {
  h = bf16rne(x);
  float hf = __uint_as_float((unsigned)h << 16);
  l = bf16rne(x - hf);
}
__device__ __forceinline__ void split4(float4 v, short4v& hv, short4v& lv) {
  unsigned short h, l;
  split1(v.x, h, l); hv[0] = (short)h; lv[0] = (short)l;
  split1(v.y, h, l); hv[1] = (short)h; lv[1] = (short)l;
  split1(v.z, h, l); hv[2] = (short)h; lv[2] = (short)l;
  split1(v.w, h, l); hv[3] = (short)h; lv[3] = (short)l;
}

// ---------------- forward / backward vector pipeline (deterministic: no atomics) ----------------

__global__ __launch_bounds__(256) void k_z1p(const float* __restrict__ x, const float* __restrict__ W1,
                                             float* __restrict__ zp1) {
  int k = blockIdx.x * 256 + threadIdx.x;
  int i0 = blockIdx.y * 256;
  float acc = 0.f;
  for (int i = i0; i < i0 + 256; ++i) acc = fmaf(x[i], W1[(size_t)i * HID + k], acc);
  zp1[(size_t)blockIdx.y * HID + k] = acc;
}

__global__ __launch_bounds__(256) void k_act1(const float* __restrict__ zp1, const float* __restrict__ b1,
                                              float* __restrict__ h1, float* __restrict__ s1,
                                              float* __restrict__ s1p) {
  int k = blockIdx.x * 256 + threadIdx.x;
  float z = b1[k];
#pragma unroll
  for (int j = 0; j < 8; ++j) z += zp1[(size_t)j * HID + k];
  float sg = 1.f / (1.f + expf(-z));
  h1[k] = (z > 20.f) ? z : log1pf(expf(z));
  s1[k] = sg;
  s1p[k] = sg * (1.f - sg);
}

__global__ __launch_bounds__(256) void k_z2p(const float* __restrict__ h1, const float* __restrict__ W2,
                                             float* __restrict__ zp2) {
  int j = blockIdx.x * 256 + threadIdx.x;
  int i0 = blockIdx.y * 256;
  float acc = 0.f;
  for (int i = i0; i < i0 + 256; ++i) acc = fmaf(h1[i], W2[(size_t)i * HID + j], acc);
  zp2[(size_t)blockIdx.y * HID + j] = acc;
}

__global__ __launch_bounds__(256) void k_act2(const float* __restrict__ zp2, const float* __restrict__ b2,
                                              const float* __restrict__ w3, float* __restrict__ g2,
                                              float* __restrict__ d2) {
  int j = blockIdx.x * 256 + threadIdx.x;
  float z = b2[j];
#pragma unroll
  for (int q = 0; q < 16; ++q) z += zp2[(size_t)q * HID + j];
  float sg = 1.f / (1.f + expf(-z));
  float w = w3[j];
  g2[j] = sg * w;
  d2[j] = sg * (1.f - sg) * w;
}

__global__ __launch_bounds__(256) void k_u(const float* __restrict__ W2, const float* __restrict__ g2,
                                           const float* __restrict__ s1, const float* __restrict__ s1p,
                                           float* __restrict__ g1, float* __restrict__ d1) {
  int w = threadIdx.x >> 6, lane = threadIdx.x & 63;
  int row = blockIdx.x * 4 + w;
  const float* p = W2 + (size_t)row * HID;
  float acc = 0.f;
  for (int j = lane; j < HID; j += 64) acc = fmaf(p[j], g2[j], acc);
  acc = wred(acc);
  if (lane == 0) {
    g1[row] = s1[row] * acc;
    d1[row] = s1p[row] * acc;
  }
}

__global__ __launch_bounds__(256) void k_dq0(const float* __restrict__ W1, const float* __restrict__ g1,
                                             float* __restrict__ dq0) {
  int w = threadIdx.x >> 6, lane = threadIdx.x & 63;
  int row = blockIdx.x * 4 + w;
  const float* p = W1 + (size_t)row * HID;
  float acc = 0.f;
  for (int k = lane; k < HID; k += 64) acc = fmaf(p[k], g1[k], acc);
  acc = wred(acc);
  if (lane == 0) dq0[row] = acc;
}

__global__ __launch_bounds__(256) void k_vp(const float* __restrict__ QT, const float* __restrict__ x,
                                            float* __restrict__ vp) {
  int l = blockIdx.x * 256 + threadIdx.x;
  int r0 = blockIdx.y * 128;
  float acc = 0.f;
  for (int r = r0; r < r0 + 128; ++r) acc = fmaf(QT[(size_t)r * HID + l], x[NH + r], acc);
  vp[(size_t)blockIdx.y * HID + l] = acc;
}

__global__ __launch_bounds__(256) void k_vred(const float* __restrict__ vp, float* __restrict__ vv) {
  int l = blockIdx.x * 256 + threadIdx.x;
  float a = 0.f;
#pragma unroll
  for (int j = 0; j < 8; ++j) a += vp[(size_t)j * HID + l];
  vv[l] = a;
}

__global__ __launch_bounds__(256) void k_rhs(const float* __restrict__ W1, const float* __restrict__ v,
                                             const float* __restrict__ dq0, float* __restrict__ rhs) {
  int w = threadIdx.x >> 6, lane = threadIdx.x & 63;
  int row = blockIdx.x * 4 + w;
  const float* p = W1 + (size_t)row * HID;
  float acc = 0.f;
  for (int l = lane; l < HID; l += 64) acc = fmaf(p[l], v[l], acc);
  acc = wred(acc);
  if (lane == 0) rhs[row] = dq0[row] - acc;
}

// ---------------- split-bf16 MFMA GEMM: 128x128 tile, BK=64, 4 waves (2x2), 4x4 MFMA tiles/wave ----
// 3-product split: (ah+al)(bh+bl) ~= ah*bh + ah*bl + al*bh (ll term ~2^-18, below fp32 rounding)
template <bool TRANSB, int MODE>
__global__ __launch_bounds__(256) void mfma_gemm(const float* __restrict__ A, int lda,
                                                 const float* __restrict__ B, int ldb,
                                                 float* __restrict__ C, int ldc, int K,
                                                 const float* __restrict__ ks,
                                                 const float* __restrict__ csc1,
                                                 const float* __restrict__ csc2,
                                                 const float* __restrict__ wadd) {
  __shared__ unsigned short Ah[2][128][40] __attribute__((aligned(16)));
  __shared__ unsigned short Al[2][128][40] __attribute__((aligned(16)));
  __shared__ unsigned short Bh[2][128][40] __attribute__((aligned(16)));
  __shared__ unsigned short Bl[2][128][40] __attribute__((aligned(16)));

  const int tid = threadIdx.x;
  const int lane = tid & 63;
  const int wid = tid >> 6;
  const int wm = wid >> 1, wn = wid & 1;
  const int bm = blockIdx.y * 128, bn = blockIdx.x * 128;
  const int frow = lane & 15;
  const int kg = lane >> 4;

  f32x4 acc[4][4];
#pragma unroll
  for (int i = 0; i < 4; ++i)
#pragma unroll
    for (int j = 0; j < 4; ++j) acc[i][j] = (f32x4){0.f, 0.f, 0.f, 0.f};

  const int ar = tid >> 1;      // A row / B col (TRANSB)
  const int ah = tid & 1;       // k-half

  for (int k0 = 0; k0 < K; k0 += 64) {
    __syncthreads();
    {  // stage A (row-major [m][k])
      const float* Ap = A + (size_t)(bm + ar) * lda + (k0 + ah * 32);
#pragma unroll
      for (int i = 0; i < 8; ++i) {
        float4 v = *(const float4*)(Ap + i * 4);
        if (MODE == 1) {
          const float* kp = ks + k0 + ah * 32 + i * 4;
          v.x *= kp[0]; v.y *= kp[1]; v.z *= kp[2]; v.w *= kp[3];
        }
        short4v hv, lv;
        split4(v, hv, lv);
        *(short4v*)&Ah[ah][ar][i * 4] = hv;
        *(short4v*)&Al[ah][ar][i * 4] = lv;
      }
    }
    if (TRANSB) {  // B row-major [n][k] -> Bs[col][k] contiguous
      const float* Bp = B + (size_t)(bn + ar) * ldb + (k0 + ah * 32);
#pragma unroll
      for (int i = 0; i < 8; ++i) {
        float4 v = *(const float4*)(Bp + i * 4);
        short4v hv, lv;
        split4(v, hv, lv);
        *(short4v*)&Bh[ah][ar][i * 4] = hv;
        *(short4v*)&Bl[ah][ar][i * 4] = lv;
      }
    } else {  // B row-major [k][n]: coalesced float4 loads, transpose write into Bs[col][k]
      int kr = tid >> 5;          // 0..7
      int cn = (tid & 31) * 4;    // col offset 0..124
#pragma unroll
      for (int p = 0; p < 8; ++p) {
        int k = p * 8 + kr;
        float4 v = *(const float4*)(B + (size_t)(k0 + k) * ldb + bn + cn);
        int kh = k >> 5, kl = k & 31;
        unsigned short h, l;
        split1(v.x, h, l); Bh[kh][cn + 0][kl] = h; Bl[kh][cn + 0][kl] = l;
        split1(v.y, h, l); Bh[kh][cn + 1][kl] = h; Bl[kh][cn + 1][kl] = l;
        split1(v.z, h, l); Bh[kh][cn + 2][kl] = h; Bl[kh][cn + 2][kl] = l;
        split1(v.w, h, l); Bh[kh][cn + 3][kl] = h; Bl[kh][cn + 3][kl] = l;
      }
    }
    __syncthreads();
#pragma unroll
    for (int kk = 0; kk < 2; ++kk) {
      short8v a_h[4], a_l[4], b_h[4], b_l[4];
#pragma unroll
      for (int mt = 0; mt < 4; ++mt) {
        int r = wm * 64 + mt * 16 + frow;
        a_h[mt] = *(const short8v*)&Ah[kk][r][kg * 8];
        a_l[mt] = *(const short8v*)&Al[kk][r][kg * 8];
      }
#pragma unroll
      for (int nt = 0; nt < 4; ++nt) {
        int c = wn * 64 + nt * 16 + frow;
        b_h[nt] = *(const short8v*)&Bh[kk][c][kg * 8];
        b_l[nt] = *(const short8v*)&Bl[kk][c][kg * 8];
      }
#pragma unroll
      for (int mt = 0; mt < 4; ++mt)
#pragma unroll
        for (int nt = 0; nt < 4; ++nt) {
          acc[mt][nt] = __builtin_amdgcn_mfma_f32_16x16x32_bf16(a_h[mt], b_l[nt], acc[mt][nt], 0, 0, 0);
          acc[mt][nt] = __builtin_amdgcn_mfma_f32_16x16x32_bf16(a_l[mt], b_h[nt], acc[mt][nt], 0, 0, 0);
          acc[mt][nt] = __builtin_amdgcn_mfma_f32_16x16x32_bf16(a_h[mt], b_h[nt], acc[mt][nt], 0, 0, 0);
        }
    }
  }
  // epilogue: C/D layout col=lane&15, row=(lane>>4)*4+j
#pragma unroll
  for (int mt = 0; mt < 4; ++mt)
#pragma unroll
    for (int nt = 0; nt < 4; ++nt) {
      int col = bn + wn * 64 + nt * 16 + frow;
      float c1 = (MODE >= 1) ? csc1[col] : 0.f;
      float c2 = (MODE == 2) ? csc2[col] : 0.f;
#pragma unroll
      for (int j = 0; j < 4; ++j) {
        int row = bm + wm * 64 + mt * 16 + kg * 4 + j;
        float v = acc[mt][nt][j];
        if (MODE == 1) v *= c1;
        if (MODE == 2) v = v * c1 + c2 * wadd[(size_t)row * HID + col];
        C[(size_t)row * ldc + col] = v;
      }
    }
}

// ---------------- augmented-matrix setup ----------------
__global__ __launch_bounds__(256) void k_setup(const float* __restrict__ dq1, const float* __restrict__ rhs,
                                               float* __restrict__ Ag) {
  int idx = blockIdx.x * 256 + threadIdx.x;  // 1024*1088
  int r = idx / LDA, c = idx % LDA;
  float v = (c < 1024) ? dq1[(size_t)r * 1024 + c] : (c == 1024 ? rhs[r] : 0.f);
  Ag[idx] = v;
}

// ---------------- blocked LU (NB=64, no pivoting), rhs as augmented col ----------------

__global__ __launch_bounds__(256) void lu_diag(float* __restrict__ Ag, int o) {
  __shared__ float T[64][65];
  int t = threadIdx.x;
  for (int idx = t; idx < 4096; idx += 256) {
    int r = idx >> 6, c = idx & 63;
    T[r][c] = Ag[(size_t)(o + r) * LDA + o + c];
  }
  __syncthreads();
  int r = t & 63, cg = t >> 6;
  for (int kk = 0; kk < 63; ++kk) {
    if (cg == 0 && r > kk) T[r][kk] /= T[kk][kk];
    __syncthreads();
    float l = (r > kk) ? T[r][kk] : 0.f;
    int c0 = cg * 16;
#pragma unroll
    for (int j = 0; j < 16; ++j) {
      int c = c0 + j;
      if (r > kk && c > kk) T[r][c] = fmaf(-l, T[kk][c], T[r][c]);
    }
    __syncthreads();
  }
  for (int idx = t; idx < 4096; idx += 256) {
    int rr = idx >> 6, c = idx & 63;
    Ag[(size_t)(o + rr) * LDA + o + c] = T[rr][c];
  }
}

__global__ __launch_bounds__(256) void lu_panel(float* __restrict__ Ag, int o, int NU) {
  __shared__ float Ds[64][65];
  __shared__ float Xs[64][65];
  __shared__ float rp[64];
  int t = threadIdx.x;
  bool isU = (int)blockIdx.x < NU;
  size_t tb;
  if (isU) tb = (size_t)o * LDA + (o + 64 + (int)blockIdx.x * 64);
  else     tb = (size_t)(o + 64 + ((int)blockIdx.x - NU) * 64) * LDA + o;
  for (int idx = t; idx < 4096; idx += 256) {
    int r = idx >> 6, c = idx & 63;
    Ds[r][c] = Ag[(size_t)(o + r) * LDA + o + c];
    Xs[r][c] = Ag[tb + (size_t)r * LDA + c];
  }
  __syncthreads();
  if (!isU && t < 64) rp[t] = 1.f / Ds[t][t];
  __syncthreads();
  if (isU) {
    int cl = t & 63, rg = t >> 6;
    for (int kk = 0; kk < 63; ++kk) {
      float xk = Xs[kk][cl];
      int i0 = rg * 16;
#pragma unroll
      for (int j = 0; j < 16; ++j) {
        int i = i0 + j;
        if (i > kk) Xs[i][cl] = fmaf(-Ds[i][kk], xk, Xs[i][cl]);
      }
      __syncthreads();
    }
  } else {
    int r = t & 63, cg = t >> 6;
    for (int kk = 0; kk < 64; ++kk) {
      if (cg == (kk >> 4)) Xs[r][kk] *= rp[kk];
      __syncthreads();
      float vk = Xs[r][kk];
      int c0 = cg * 16;
#pragma unroll
      for (int j = 0; j < 16; ++j) {
        int m = c0 + j;
        if (m > kk) Xs[r][m] = fmaf(-vk, Ds[kk][m], Xs[r][m]);
      }
      __syncthreads();
    }
  }
  __syncthreads();
  for (int idx = t; idx < 4096; idx += 256) {
    int r = idx >> 6, c = idx & 63;
    Ag[tb + (size_t)r * LDA + c] = Xs[r][c];
  }
}

__global__ __launch_bounds__(256) void lu_schur(float* __restrict__ Ag, int o) {
  __shared__ float Ls[64][65];
  __shared__ float Us[64][65];
  int t = threadIdx.x;
  int c0 = o + 64 + blockIdx.x * 64;
  int r0 = o + 64 + blockIdx.y * 64;
  for (int idx = t; idx < 4096; idx += 256) {
    int r = idx >> 6, q = idx & 63;
    Ls[q][r] = Ag[(size_t)(r0 + r) * LDA + o + q];
    Us[r][q] = Ag[(size_t)(o + r) * LDA + c0 + q];
  }
  __syncthreads();
  int tm = (t >> 4) * 4, tn = (t & 15) * 4;
  float acc[4][4];
#pragma unroll
  for (int i = 0; i < 4; ++i)
#pragma unroll
    for (int j = 0; j < 4; ++j) acc[i][j] = 0.f;
#pragma unroll 8
  for (int kk = 0; kk < 64; ++kk) {
    float a[4], b[4];
#pragma unroll
    for (int i = 0; i < 4; ++i) a[i] = Ls[kk][tm + i];
#pragma unroll
    for (int j = 0; j < 4; ++j) b[j] = Us[kk][tn + j];
#pragma unroll
    for (int i = 0; i < 4; ++i)
#pragma unroll
      for (int j = 0; j < 4; ++j) acc[i][j] = fmaf(a[i], b[j], acc[i][j]);
  }
#pragma unroll
  for (int i = 0; i < 4; ++i)
#pragma unroll
    for (int j = 0; j < 4; ++j) Ag[(size_t)(r0 + tm + i) * LDA + c0 + tn + j] -= acc[i][j];
}

// ---------------- whole-triangular-solve kernels (single block, 1024 threads, left-looking) -------

__global__ __launch_bounds__(1024) void bs_all(const float* __restrict__ Ag, float* __restrict__ yb) {
  __shared__ float ys[1024];
  __shared__ float Td[64][65];
  int t = threadIdx.x;
  int lane = t & 63, wg = t >> 6;
  ys[t] = Ag[(size_t)t * LDA + 1024];
  __syncthreads();
  for (int kb = 15; kb >= 0; --kb) {
    int o = kb * 64;
    for (int idx = t; idx < 4096; idx += 1024) {
      int r = idx >> 6, c = idx & 63;
      Td[r][c] = Ag[(size_t)(o + r) * LDA + o + c];
    }
    if (kb < 15) {
      // lazy update: rows o..o+63 -= dot(Ag[row][o+64..1023], ys[o+64..1023])
      int r = o + wg * 4;
      float a0 = 0.f, a1 = 0.f, a2 = 0.f, a3 = 0.f;
      for (int c = o + 64 + lane; c < 1024; c += 64) {
        float yc = ys[c];
        a0 = fmaf(Ag[(size_t)(r + 0) * LDA + c], yc, a0);
        a1 = fmaf(Ag[(size_t)(r + 1) * LDA + c], yc, a1);
        a2 = fmaf(Ag[(size_t)(r + 2) * LDA + c], yc, a2);
        a3 = fmaf(Ag[(size_t)(r + 3) * LDA + c], yc, a3);
      }
      a0 = wred(a0); a1 = wred(a1); a2 = wred(a2); a3 = wred(a3);
      __syncthreads();
      if (lane == 0) { ys[r] -= a0; ys[r + 1] -= a1; ys[r + 2] -= a2; ys[r + 3] -= a3; }
    }
    __syncthreads();
    if (t < 64) {
      float yv = ys[o + t];
      float rpv = 1.f / Td[t][t];
#pragma unroll 16
      for (int kk = 63; kk >= 0; --kk) {
        float xk = __shfl(yv * rpv, kk, 64);
        if (t == kk) yv = xk;
        else if (t < kk) yv = fmaf(-Td[t][kk], xk, yv);
      }
      ys[o + t] = yv;
    }
    __syncthreads();
  }
  yb[t] = ys[t];
}

__global__ __launch_bounds__(256) void k_resid(const float* __restrict__ dq1, const float* __restrict__ x0,
                                               const float* __restrict__ rhs, float* __restrict__ rv) {
  int w = threadIdx.x >> 6, lane = threadIdx.x & 63;
  int row = blockIdx.x * 4 + w;
  const float* p = dq1 + (size_t)row * 1024;
  float acc = 0.f;
  for (int j = lane; j < 1024; j += 64) acc = fmaf(p[j], x0[j], acc);
  acc = wred(acc);
  if (lane == 0) rv[row] = rhs[row] - acc;
}

__global__ __launch_bounds__(1024) void fsbs_all(const float* __restrict__ Ag, const float* __restrict__ rv,
                                                 const float* __restrict__ yb, float* __restrict__ out) {
  __shared__ float ys[1024];
  __shared__ float Td[64][65];
  int t = threadIdx.x;
  int lane = t & 63, wg = t >> 6;
  ys[t] = rv[t];
  __syncthreads();
  // forward substitution (unit lower), left-looking
  for (int kb = 0; kb < 16; ++kb) {
    int o = kb * 64;
    for (int idx = t; idx < 4096; idx += 1024) {
      int r = idx >> 6, c = idx & 63;
      Td[r][c] = Ag[(size_t)(o + r) * LDA + o + c];
    }
    if (kb > 0) {
      int r = o + wg * 4;
      float a0 = 0.f, a1 = 0.f, a2 = 0.f, a3 = 0.f;
      for (int c = lane; c < o; c += 64) {
        float yc = ys[c];
        a0 = fmaf(Ag[(size_t)(r + 0) * LDA + c], yc, a0);
        a1 = fmaf(Ag[(size_t)(r + 1) * LDA + c], yc, a1);
        a2 = fmaf(Ag[(size_t)(r + 2) * LDA + c], yc, a2);
        a3 = fmaf(Ag[(size_t)(r + 3) * LDA + c], yc, a3);
      }
      a0 = wred(a0); a1 = wred(a1); a2 = wred(a2); a3 = wred(a3);
      __syncthreads();
      if (lane == 0) { ys[r] -= a0; ys[r + 1] -= a1; ys[r + 2] -= a2; ys[r + 3] -= a3; }
    }
    __syncthreads();
    if (t < 64) {
      float yv = ys[o + t];
#pragma unroll 16
      for (int kk = 0; kk < 63; ++kk) {
        float xk = __shfl(yv, kk, 64);
        if (t > kk) yv = fmaf(-Td[t][kk], xk, yv);
      }
      ys[o + t] = yv;
    }
    __syncthreads();
  }
  // back substitution, left-looking
  for (int kb = 15; kb >= 0; --kb) {
    int o = kb * 64;
    for (int idx = t; idx < 4096; idx += 1024) {
      int r = idx >> 6, c = idx & 63;
      Td[r][c] = Ag[(size_t)(o + r) * LDA + o + c];
    }
    if (kb < 15) {
      int r = o + wg * 4;
      float a0 = 0.f, a1 = 0.f, a2 = 0.f, a3 = 0.f;
      for (int c = o + 64 + lane; c < 1024; c += 64) {
        float yc = ys[c];
        a0 = fmaf(Ag[(size_t)(r + 0) * LDA + c], yc, a0);
        a1 = fmaf(Ag[(size_t)(r + 1) * LDA + c], yc, a1);
        a2 = fmaf(Ag[(size_t)(r + 2) * LDA + c], yc, a2);
        a3 = fmaf(Ag[(size_t)(r + 3) * LDA + c], yc, a3);
      }
      a0 = wred(a0); a1 = wred(a1); a2 = wred(a2); a3 = wred(a3);
      __syncthreads();
      if (lane == 0) { ys[r] -= a0; ys[r + 1] -= a1; ys[r + 2] -= a2; ys[r + 3] -= a3; }
    }
    __syncthreads();
    if (t < 64) {
      float yv = ys[o + t];
      float rpv = 1.f / Td[t][t];
#pragma unroll 16
      for (int kk = 63; kk >= 0; --kk) {
        float xk = __shfl(yv * rpv, kk, 64);
        if (t == kk) yv = xk;
        else if (t < kk) yv = fmaf(-Td[t][kk], xk, yv);
      }
      ys[o + t] = yv;
    }
    __syncthreads();
  }
  out[t] = yb[t] + ys[t];
}

// ---------------- launcher ----------------

extern "C" void kernel_launch(void* const* d_in, const int* in_sizes, int n_in, void* d_out,
                              int out_size, void* d_ws, size_t ws_size, hipStream_t stream) {
  const float* x  = (const float*)d_in[0];
  const float* W1 = (const float*)d_in[1];
  const float* b1 = (const float*)d_in[2];
  const float* W2 = (const float*)d_in[3];
  const float* b2 = (const float*)d_in[4];
  const float* W3 = (const float*)d_in[5];
  float* out = (float*)d_out;
  float* ws = (float*)d_ws;

  // workspace layout (floats)
  float* h1  = ws + 0;
  float* s1  = ws + 4096;
  float* s1p = ws + 8192;
  float* d1  = ws + 12288;
  float* g2  = ws + 16384;
  float* d2  = ws + 20480;
  float* g1  = ws + 24576;
  float* vv  = ws + 28672;
  float* dq0 = ws + 32768;
  float* rhs = ws + 33792;
  float* yb  = ws + 34816;
  float* rv  = ws + 35840;
  float* Bbs = ws + 65536;
  float* QT  = Bbs + (size_t)1024 * HID;
  float* Ag  = QT + (size_t)1024 * HID;
  float* dq1 = Ag + (size_t)1024 * LDA;

  // deterministic-reduction partial buffers, aliased into Ag (dead until k_setup)
  float* zp1 = Ag;            //  8 x 4096
  float* zp2 = Ag + 32768;    // 16 x 4096
  float* vp  = Ag + 98304;    //  8 x 4096

  const float* W1b = W1 + (size_t)NH * HID;

  // forward + backward vectors (no atomics anywhere)
  k_z1p<<<dim3(16, 8), 256, 0, stream>>>(x, W1, zp1);
  k_act1<<<16, 256, 0, stream>>>(zp1, b1, h1, s1, s1p);
  k_z2p<<<dim3(16, 16), 256, 0, stream>>>(h1, W2, zp2);
  k_act2<<<16, 256, 0, stream>>>(zp2, b2, W3, g2, d2);
  k_u<<<1024, 256, 0, stream>>>(W2, g2, s1, s1p, g1, d1);
  k_dq0<<<256, 256, 0, stream>>>(W1, g1, dq0);

  // Hessian blocks via split-bf16 MFMA
  mfma_gemm<false, 1><<<dim3(32, 8), 256, 0, stream>>>(
      W1b, HID, W2, HID, Bbs, HID, HID, s1, d2, nullptr, nullptr);
  mfma_gemm<true, 2><<<dim3(32, 8), 256, 0, stream>>>(
      Bbs, HID, W2, HID, QT, HID, HID, nullptr, s1, d1, W1b);
  mfma_gemm<true, 0><<<dim3(8, 8), 256, 0, stream>>>(
      W1b, HID, QT, HID, dq1, 1024, HID, nullptr, nullptr, nullptr, nullptr);

  // rhs = dq0 - dq2 @ x[n:]  via vv = QT^T @ x[n:]
  k_vp<<<dim3(16, 8), 256, 0, stream>>>(QT, x, vp);
  k_vred<<<16, 256, 0, stream>>>(vp, vv);
  k_rhs<<<256, 256, 0, stream>>>(W1, vv, dq0, rhs);
  k_setup<<<(1024 * LDA) / 256, 256, 0, stream>>>(dq1, rhs, Ag);

  // blocked LU, rhs carried in augmented column
  for (int kb = 0; kb < 16; ++kb) {
    int o = kb * 64;
    int NU = 16 - kb;
    int NL = 15 - kb;
    lu_diag<<<1, 256, 0, stream>>>(Ag, o);
    lu_panel<<<NU + NL, 256, 0, stream>>>(Ag, o, NU);
    if (NL > 0) lu_schur<<<dim3(NU, NL), 256, 0, stream>>>(Ag, o);
  }

  // solve + one iterative-refinement pass
  bs_all<<<1, 1024, 0, stream>>>(Ag, yb);
  k_resid<<<256, 256, 0, stream>>>(dq1, yb, rhs, rv);
  fsbs_all<<<1, 1024, 0, stream>>>(Ag, rv, yb, out);
}